// Round 1
// baseline (346.386 us; speedup 1.0000x reference)
//
#include <hip/hip_runtime.h>
#include <hip/hip_bf16.h>

using f32x4  = __attribute__((ext_vector_type(4))) float;
using bf16x8 = __attribute__((ext_vector_type(8))) short;

__device__ __forceinline__ unsigned short f2bf(float f) {
    union { float f; unsigned int u; } v; v.f = f;
    unsigned int r = v.u + 0x7fffu + ((v.u >> 16) & 1u);
    return (unsigned short)(r >> 16);
}

// ---------------- prep: dtype converts / transposes ----------------
__global__ void prep_kernel(const float* __restrict__ E, const float* __restrict__ Wsc0,
                            const float* __restrict__ Wfw, const float* __restrict__ bfw,
                            const float* __restrict__ Wbw, const float* __restrict__ bbw,
                            const float* __restrict__ Wlin,
                            unsigned short* __restrict__ E16, unsigned short* __restrict__ W0cT,
                            unsigned short* __restrict__ WcatT, unsigned short* __restrict__ WlinT,
                            float* __restrict__ bsumS) {
    const int NE = 512 * 256;
    const int NW0 = 512 * 256;      // enumerated (k, f)
    const int NCAT = 2 * 1024 * 256; // (l,d,r,k,e)
    const int NLIN = 2 * 256 * 256;  // (l,f,d)
    const int NB = 2 * 256;
    int total = NE + NW0 + NCAT + NLIN + NB;
    for (int idx = blockIdx.x * blockDim.x + threadIdx.x; idx < total;
         idx += gridDim.x * blockDim.x) {
        int t = idx;
        if (t < NE) { E16[t] = f2bf(E[t]); continue; }
        t -= NE;
        if (t < NW0) {
            int k = t >> 9, f = t & 511;
            W0cT[f * 256 + k] = f2bf(Wsc0[(512 + k) * 512 + f]);
            continue;
        }
        t -= NW0;
        if (t < NCAT) {
            int e = t & 127, k = (t >> 7) & 255, r = (t >> 15) & 3, d = (t >> 17) & 1, l = t >> 18;
            const float* src = (d == 0) ? Wfw : Wbw;
            float v = src[((l * 4 + r) * 256 + k) * 128 + e];
            WcatT[(l * 1024 + d * 512 + r * 128 + e) * 256 + k] = f2bf(v);
            continue;
        }
        t -= NCAT;
        if (t < NLIN) {
            int d = t & 255, f = (t >> 8) & 255, l = t >> 16;
            WlinT[(l * 256 + d) * 256 + f] = f2bf(Wlin[(l * 256 + f) * 256 + d]);
            continue;
        }
        t -= NLIN;
        {
            int f = t & 255, l = t >> 8;
            float s = 0.f;
            if (f < 128) { for (int r = 0; r < 4; ++r) s += bbw[(l * 4 + r) * 128 + f]; }
            else         { for (int r = 0; r < 4; ++r) s += bfw[(l * 4 + r) * 128 + (f - 128)]; }
            bsumS[l * 256 + f] = s;
        }
    }
}

// ---------------- U = E@W0a, V = E@W0b (fp32) ----------------
__global__ __launch_bounds__(512) void uv_kernel(const float* __restrict__ E,
                                                 const float* __restrict__ Wsc0,
                                                 float* __restrict__ U, float* __restrict__ V) {
    __shared__ float sE[8][256];
    int j0 = blockIdx.x * 8;
    int tid = threadIdx.x;
    for (int t = tid; t < 2048; t += 512) sE[t >> 8][t & 255] = E[j0 * 256 + t];
    __syncthreads();
    int f = tid;
    float u[8] = {0,0,0,0,0,0,0,0}, v[8] = {0,0,0,0,0,0,0,0};
    for (int k = 0; k < 256; ++k) {
        float wa = Wsc0[k * 512 + f];
        float wb = Wsc0[(256 + k) * 512 + f];
#pragma unroll
        for (int jj = 0; jj < 8; ++jj) { u[jj] += sE[jj][k] * wa; v[jj] += sE[jj][k] * wb; }
    }
#pragma unroll
    for (int jj = 0; jj < 8; ++jj) {
        U[(j0 + jj) * 512 + f] = u[jj];
        V[(j0 + jj) * 512 + f] = v[jj];
    }
}

// ---------------- pair scorer: T=(Ei∘Ej)@W0c, +U+V+b0, relu, @W_sc1, softmax -> A, AT ----------------
__global__ __launch_bounds__(512, 4) void pair_kernel(
    const float* __restrict__ E, const unsigned short* __restrict__ W0cT,
    const float* __restrict__ U, const float* __restrict__ V,
    const float* __restrict__ b0, const float* __restrict__ W1, const float* __restrict__ b1,
    unsigned short* __restrict__ A16, unsigned short* __restrict__ AT16) {

    __shared__ unsigned short prodL[64 * 256];   // 32 KB, XOR-swizzled rows of 512B
    __shared__ float partial[64 * 4 * 33];       // stride 33 -> conflict-free reduce
    __shared__ float scoresL[64 * 4];

    const int i = blockIdx.x;
    const int j0 = blockIdx.y * 64;
    const int tid = threadIdx.x;
    const int lane = tid & 63;
    const int w = tid >> 6;
    const int l15 = lane & 15, l4 = lane >> 4;

    // stage product tile (64 j-rows x 256 k) as bf16
    {
        int m = tid >> 3;
        int kbase = (tid & 7) * 32;
        const float4* ej = (const float4*)(E + (j0 + m) * 256 + kbase);
        const float4* ei = (const float4*)(E + i * 256 + kbase);
        char* base = (char*)prodL;
#pragma unroll
        for (int c = 0; c < 8; ++c) {
            float4 a = ej[c], b = ei[c];
            unsigned short p0 = f2bf(a.x * b.x), p1 = f2bf(a.y * b.y);
            unsigned short p2 = f2bf(a.z * b.z), p3 = f2bf(a.w * b.w);
            int k = kbase + c * 4;
            int byteoff = m * 512 + ((k * 2) ^ ((m & 7) << 4));
            uint2 val;
            val.x = (unsigned)p0 | ((unsigned)p1 << 16);
            val.y = (unsigned)p2 | ((unsigned)p3 << 16);
            *(uint2*)(base + byteoff) = val;
        }
    }
    __syncthreads();

    f32x4 acc[4][4];
#pragma unroll
    for (int a_ = 0; a_ < 4; ++a_)
#pragma unroll
        for (int b_ = 0; b_ < 4; ++b_) acc[a_][b_] = (f32x4){0.f, 0.f, 0.f, 0.f};

    const char* pbase = (const char*)prodL;
    for (int kk = 0; kk < 8; ++kk) {
        bf16x8 afr[4], bfr[4];
#pragma unroll
        for (int mb = 0; mb < 4; ++mb) {
            int row = mb * 16 + l15;
            int off = row * 512 + ((kk * 64 + l4 * 16) ^ ((row & 7) << 4));
            afr[mb] = *(const bf16x8*)(pbase + off);
        }
#pragma unroll
        for (int nb = 0; nb < 4; ++nb) {
            int fcol = w * 64 + nb * 16 + l15;
            bfr[nb] = *(const bf16x8*)(W0cT + fcol * 256 + kk * 32 + l4 * 8);
        }
#pragma unroll
        for (int mb = 0; mb < 4; ++mb)
#pragma unroll
            for (int nb = 0; nb < 4; ++nb)
                acc[mb][nb] = __builtin_amdgcn_mfma_f32_16x16x32_bf16(afr[mb], bfr[nb], acc[mb][nb], 0, 0, 0);
    }

    // epilogue: h = relu(acc + U[j] + V[i] + b0); partial scores = h @ W_sc1
    float b0v[4], Vv[4];
    float4 w1v[4];
#pragma unroll
    for (int nb = 0; nb < 4; ++nb) {
        int fcol = w * 64 + nb * 16 + l15;
        b0v[nb] = b0[fcol];
        Vv[nb] = V[i * 512 + fcol];
        w1v[nb] = *(const float4*)(W1 + fcol * 4);
    }
#pragma unroll
    for (int mb = 0; mb < 4; ++mb) {
        float s2[4][4];
#pragma unroll
        for (int reg = 0; reg < 4; ++reg) {
            s2[reg][0] = 0.f; s2[reg][1] = 0.f; s2[reg][2] = 0.f; s2[reg][3] = 0.f;
            int m = mb * 16 + l4 * 4 + reg;
            int j = j0 + m;
            const float* Urow = U + j * 512;
#pragma unroll
            for (int nb = 0; nb < 4; ++nb) {
                int fcol = w * 64 + nb * 16 + l15;
                float h = acc[mb][nb][reg] + Urow[fcol] + Vv[nb] + b0v[nb];
                h = fmaxf(h, 0.f);
                s2[reg][0] += h * w1v[nb].x;
                s2[reg][1] += h * w1v[nb].y;
                s2[reg][2] += h * w1v[nb].z;
                s2[reg][3] += h * w1v[nb].w;
            }
        }
#pragma unroll
        for (int reg = 0; reg < 4; ++reg)
#pragma unroll
            for (int r = 0; r < 4; ++r) {
                float vs = s2[reg][r];
                vs += __shfl_xor(vs, 1);
                vs += __shfl_xor(vs, 2);
                s2[reg][r] = vs;
            }
        if ((lane & 3) == 0) {
            int slot = w * 4 + ((lane & 15) >> 2);
#pragma unroll
            for (int reg = 0; reg < 4; ++reg) {
                int m = mb * 16 + l4 * 4 + reg;
#pragma unroll
                for (int r = 0; r < 4; ++r) partial[(m * 4 + r) * 33 + slot] = s2[reg][r];
            }
        }
    }
    __syncthreads();
    if (tid < 256) {
        int m = tid >> 2, r = tid & 3;
        float sc = b1[r];
#pragma unroll
        for (int p = 0; p < 32; ++p) sc += partial[(m * 4 + r) * 33 + p];
        scoresL[m * 4 + r] = sc;
    }
    __syncthreads();
    if (tid < 64) {
        int m = tid, j = j0 + m;
        float s0 = scoresL[m * 4 + 0], s1 = scoresL[m * 4 + 1];
        float sA = scoresL[m * 4 + 2], sB = scoresL[m * 4 + 3];
        float mx = fmaxf(fmaxf(s0, s1), fmaxf(sA, sB));
        float e0 = __expf(s0 - mx), e1 = __expf(s1 - mx), e2 = __expf(sA - mx), e3 = __expf(sB - mx);
        float inv = 1.f / (e0 + e1 + e2 + e3);
        float p_[4] = {e0 * inv, e1 * inv, e2 * inv, e3 * inv};
        if (j == i) { p_[0] = p_[1] = p_[2] = p_[3] = 0.f; }
#pragma unroll
        for (int r = 0; r < 4; ++r) {
            unsigned short pb = f2bf(p_[r]);
            A16[(r * 512 + i) * 512 + j] = pb;
            AT16[(r * 512 + j) * 512 + i] = pb;
        }
    }
}

// ---------------- small GEMM helpers (64x64 tiles, NT layout: both operands [idx][k]) ----------------
__device__ __forceinline__ void stage_tile(unsigned short* lds, const unsigned short* g, int ld, int tid) {
#pragma unroll
    for (int it = 0; it < 2; ++it) {
        int c = tid + it * 256;
        int row = c >> 3, slot = c & 7;
        uint4 v = *(const uint4*)(g + row * ld + slot * 8);
        *(uint4*)((char*)lds + row * 128 + ((slot ^ (row & 7)) << 4)) = v;
    }
}
__device__ __forceinline__ bf16x8 frag_read(const unsigned short* lds, int row, int kk, int l4) {
    return *(const bf16x8*)((const char*)lds + row * 128 + (((kk * 4 + l4) ^ (row & 7)) << 4));
}

// supT[c][j] = sum_k WcatT[c][k] * x16[j][k]
__global__ __launch_bounds__(256) void c1_kernel(const unsigned short* __restrict__ WcatT,
                                                 const unsigned short* __restrict__ x16,
                                                 unsigned short* __restrict__ supT, int l) {
    __shared__ unsigned short lA[64 * 64], lB[64 * 64];
    int c0 = blockIdx.x * 64, jt0 = blockIdx.y * 64;
    int tid = threadIdx.x, lane = tid & 63, w = tid >> 6;
    int wr = (w >> 1) * 32, wc = (w & 1) * 32;
    int l15 = lane & 15, l4 = lane >> 4;
    const unsigned short* Abase = WcatT + l * 1024 * 256 + c0 * 256;
    const unsigned short* Bbase = x16 + jt0 * 256;
    f32x4 acc[2][2];
#pragma unroll
    for (int a_ = 0; a_ < 2; ++a_)
#pragma unroll
        for (int b_ = 0; b_ < 2; ++b_) acc[a_][b_] = (f32x4){0.f, 0.f, 0.f, 0.f};
    for (int ks = 0; ks < 4; ++ks) {
        __syncthreads();
        stage_tile(lA, Abase + ks * 64, 256, tid);
        stage_tile(lB, Bbase + ks * 64, 256, tid);
        __syncthreads();
#pragma unroll
        for (int kk = 0; kk < 2; ++kk) {
            bf16x8 af[2], bf_[2];
#pragma unroll
            for (int mb = 0; mb < 2; ++mb) af[mb] = frag_read(lA, wr + mb * 16 + l15, kk, l4);
#pragma unroll
            for (int nb = 0; nb < 2; ++nb) bf_[nb] = frag_read(lB, wc + nb * 16 + l15, kk, l4);
#pragma unroll
            for (int mb = 0; mb < 2; ++mb)
#pragma unroll
                for (int nb = 0; nb < 2; ++nb)
                    acc[mb][nb] = __builtin_amdgcn_mfma_f32_16x16x32_bf16(af[mb], bf_[nb], acc[mb][nb], 0, 0, 0);
        }
    }
#pragma unroll
    for (int mb = 0; mb < 2; ++mb)
#pragma unroll
        for (int nb = 0; nb < 2; ++nb)
#pragma unroll
            for (int reg = 0; reg < 4; ++reg) {
                int c = c0 + wr + mb * 16 + l4 * 4 + reg;
                int j = jt0 + wc + nb * 16 + l15;
                supT[c * 512 + j] = f2bf(acc[mb][nb][reg]);
            }
}

// relS[i][f] = relu( sum_r (A or AT)[r] @ sup[r] + bsum )
__global__ __launch_bounds__(256) void c2_kernel(const unsigned short* __restrict__ A16,
                                                 const unsigned short* __restrict__ AT16,
                                                 const unsigned short* __restrict__ supT,
                                                 const float* __restrict__ bsumS,
                                                 unsigned short* __restrict__ relS, int l) {
    __shared__ unsigned short lA[64 * 64], lB[64 * 64];
    int i0 = blockIdx.x * 64, f0 = blockIdx.y * 64;
    bool bw = (f0 < 128);
    int e0 = bw ? f0 : (f0 - 128);
    const unsigned short* Am = bw ? AT16 : A16;
    int tid = threadIdx.x, lane = tid & 63, w = tid >> 6;
    int wr = (w >> 1) * 32, wc = (w & 1) * 32;
    int l15 = lane & 15, l4 = lane >> 4;
    f32x4 acc[2][2];
#pragma unroll
    for (int a_ = 0; a_ < 2; ++a_)
#pragma unroll
        for (int b_ = 0; b_ < 2; ++b_) acc[a_][b_] = (f32x4){0.f, 0.f, 0.f, 0.f};
    for (int r = 0; r < 4; ++r) {
        const unsigned short* Abase = Am + r * 512 * 512 + i0 * 512;
        const unsigned short* Bbase = supT + ((bw ? 512 : 0) + r * 128 + e0) * 512;
        for (int ks = 0; ks < 8; ++ks) {
            __syncthreads();
            stage_tile(lA, Abase + ks * 64, 512, tid);
            stage_tile(lB, Bbase + ks * 64, 512, tid);
            __syncthreads();
#pragma unroll
            for (int kk = 0; kk < 2; ++kk) {
                bf16x8 af[2], bf_[2];
#pragma unroll
                for (int mb = 0; mb < 2; ++mb) af[mb] = frag_read(lA, wr + mb * 16 + l15, kk, l4);
#pragma unroll
                for (int nb = 0; nb < 2; ++nb) bf_[nb] = frag_read(lB, wc + nb * 16 + l15, kk, l4);
#pragma unroll
                for (int mb = 0; mb < 2; ++mb)
#pragma unroll
                    for (int nb = 0; nb < 2; ++nb)
                        acc[mb][nb] = __builtin_amdgcn_mfma_f32_16x16x32_bf16(af[mb], bf_[nb], acc[mb][nb], 0, 0, 0);
            }
        }
    }
#pragma unroll
    for (int mb = 0; mb < 2; ++mb)
#pragma unroll
        for (int nb = 0; nb < 2; ++nb)
#pragma unroll
            for (int reg = 0; reg < 4; ++reg) {
                int ii = i0 + wr + mb * 16 + l4 * 4 + reg;
                int f = f0 + wc + nb * 16 + l15;
                float vv = acc[mb][nb][reg] + bsumS[l * 256 + f];
                relS[ii * 256 + f] = f2bf(fmaxf(vv, 0.f));
            }
}

// xnew[i][d] = relS @ Wlin + blin + xold ; also bf16 copy
__global__ __launch_bounds__(256) void c3_kernel(const unsigned short* __restrict__ relS,
                                                 const unsigned short* __restrict__ WlinT,
                                                 const float* __restrict__ blin,
                                                 const float* __restrict__ xold,
                                                 float* __restrict__ xnew,
                                                 unsigned short* __restrict__ x16out, int l) {
    __shared__ unsigned short lA[64 * 64], lB[64 * 64];
    int i0 = blockIdx.x * 64, d0 = blockIdx.y * 64;
    int tid = threadIdx.x, lane = tid & 63, w = tid >> 6;
    int wr = (w >> 1) * 32, wc = (w & 1) * 32;
    int l15 = lane & 15, l4 = lane >> 4;
    const unsigned short* Abase = relS + i0 * 256;
    const unsigned short* Bbase = WlinT + l * 256 * 256 + d0 * 256;
    f32x4 acc[2][2];
#pragma unroll
    for (int a_ = 0; a_ < 2; ++a_)
#pragma unroll
        for (int b_ = 0; b_ < 2; ++b_) acc[a_][b_] = (f32x4){0.f, 0.f, 0.f, 0.f};
    for (int ks = 0; ks < 4; ++ks) {
        __syncthreads();
        stage_tile(lA, Abase + ks * 64, 256, tid);
        stage_tile(lB, Bbase + ks * 64, 256, tid);
        __syncthreads();
#pragma unroll
        for (int kk = 0; kk < 2; ++kk) {
            bf16x8 af[2], bf_[2];
#pragma unroll
            for (int mb = 0; mb < 2; ++mb) af[mb] = frag_read(lA, wr + mb * 16 + l15, kk, l4);
#pragma unroll
            for (int nb = 0; nb < 2; ++nb) bf_[nb] = frag_read(lB, wc + nb * 16 + l15, kk, l4);
#pragma unroll
            for (int mb = 0; mb < 2; ++mb)
#pragma unroll
                for (int nb = 0; nb < 2; ++nb)
                    acc[mb][nb] = __builtin_amdgcn_mfma_f32_16x16x32_bf16(af[mb], bf_[nb], acc[mb][nb], 0, 0, 0);
        }
    }
#pragma unroll
    for (int mb = 0; mb < 2; ++mb)
#pragma unroll
        for (int nb = 0; nb < 2; ++nb)
#pragma unroll
            for (int reg = 0; reg < 4; ++reg) {
                int ii = i0 + wr + mb * 16 + l4 * 4 + reg;
                int dd = d0 + wc + nb * 16 + l15;
                float vv = acc[mb][nb][reg] + blin[l * 256 + dd] + xold[ii * 256 + dd];
                xnew[ii * 256 + dd] = vv;
                x16out[ii * 256 + dd] = f2bf(vv);
            }
}

extern "C" void kernel_launch(void* const* d_in, const int* in_sizes, int n_in,
                              void* d_out, int out_size, void* d_ws, size_t ws_size,
                              hipStream_t stream) {
    const float* E    = (const float*)d_in[0];
    const float* Wsc0 = (const float*)d_in[1];
    const float* bsc0 = (const float*)d_in[2];
    const float* Wsc1 = (const float*)d_in[3];
    const float* bsc1 = (const float*)d_in[4];
    const float* Wfw  = (const float*)d_in[5];
    const float* bfw  = (const float*)d_in[6];
    const float* Wbw  = (const float*)d_in[7];
    const float* bbw  = (const float*)d_in[8];
    const float* Wlin = (const float*)d_in[9];
    const float* blin = (const float*)d_in[10];
    float* out = (float*)d_out;

    char* ws = (char*)d_ws;
    size_t off = 0;
    unsigned short* E16   = (unsigned short*)(ws + off); off += 512 * 256 * 2;        // 256 KB
    unsigned short* W0cT  = (unsigned short*)(ws + off); off += 512 * 256 * 2;        // 256 KB
    unsigned short* WcatT = (unsigned short*)(ws + off); off += 2 * 1024 * 256 * 2;   // 1 MB
    unsigned short* WlinT = (unsigned short*)(ws + off); off += 2 * 256 * 256 * 2;    // 256 KB
    float* bsumS          = (float*)(ws + off);          off += 2 * 256 * 4;          // 2 KB
    float* U              = (float*)(ws + off);          off += 512 * 512 * 4;        // 1 MB
    float* V              = (float*)(ws + off);          off += 512 * 512 * 4;        // 1 MB
    unsigned short* A16   = (unsigned short*)(ws + off); off += 4 * 512 * 512 * 2;    // 2 MB
    unsigned short* AT16  = (unsigned short*)(ws + off); off += 4 * 512 * 512 * 2;    // 2 MB
    unsigned short* supT  = (unsigned short*)(ws + off); off += 1024 * 512 * 2;       // 1 MB
    unsigned short* relS  = (unsigned short*)(ws + off); off += 512 * 256 * 2;        // 256 KB
    float* xf1            = (float*)(ws + off);          off += 512 * 256 * 4;        // 512 KB
    unsigned short* x16_1 = (unsigned short*)(ws + off); off += 512 * 256 * 2;        // 256 KB

    prep_kernel<<<1024, 256, 0, stream>>>(E, Wsc0, Wfw, bfw, Wbw, bbw, Wlin,
                                          E16, W0cT, WcatT, WlinT, bsumS);
    uv_kernel<<<64, 512, 0, stream>>>(E, Wsc0, U, V);
    pair_kernel<<<dim3(512, 8), 512, 0, stream>>>(E, W0cT, U, V, bsc0, Wsc1, bsc1, A16, AT16);

    for (int l = 0; l < 2; ++l) {
        const unsigned short* xin16 = (l == 0) ? E16 : x16_1;
        const float* xoldf = (l == 0) ? E : xf1;
        float* xout = (l == 0) ? xf1 : out;
        c1_kernel<<<dim3(16, 8), 256, 0, stream>>>(WcatT, xin16, supT, l);
        c2_kernel<<<dim3(8, 4), 256, 0, stream>>>(A16, AT16, supT, bsumS, relS, l);
        c3_kernel<<<dim3(8, 4), 256, 0, stream>>>(relS, WlinT, blin, xoldf, xout, x16_1, l);
    }
    (void)in_sizes; (void)n_in; (void)out_size; (void)ws_size;
}

// Round 2
// 302.677 us; speedup vs baseline: 1.1444x; 1.1444x over previous
//
#include <hip/hip_runtime.h>
#include <hip/hip_bf16.h>

using f32x4  = __attribute__((ext_vector_type(4))) float;
using bf16x8 = __attribute__((ext_vector_type(8))) short;

__device__ __forceinline__ unsigned short f2bf(float f) {
    union { __hip_bfloat16 h; unsigned short u; } cv;
    cv.h = __float2bfloat16(f);
    return cv.u;
}
__device__ __forceinline__ unsigned int pack2bf(float lo, float hi) {
    float2 t; t.x = lo; t.y = hi;
    union { __hip_bfloat162 h; unsigned int u; } cv;
    cv.h = __float22bfloat162_rn(t);
    return cv.u;
}

// ---------------- prep (blocks 0..511) + uv (blocks 512..575) fat kernel ----------------
__global__ __launch_bounds__(512) void prep_uv_kernel(
        const float* __restrict__ E, const float* __restrict__ Wsc0, const float* __restrict__ bsc0,
        const float* __restrict__ Wfw, const float* __restrict__ bfw,
        const float* __restrict__ Wbw, const float* __restrict__ bbw,
        const float* __restrict__ Wlin,
        unsigned short* __restrict__ E16, unsigned short* __restrict__ W0cT,
        unsigned short* __restrict__ WcatT, unsigned short* __restrict__ WlinT,
        float* __restrict__ bsumS, float* __restrict__ U, float* __restrict__ V) {
    __shared__ float sE[8][256];
    if (blockIdx.x < 512) {
        const int NE = 131072, NW0 = 131072, NCAT = 524288, NLIN = 131072;
        const int total = NE + NW0 + NCAT + NLIN + 512;
        for (int idx = blockIdx.x * 512 + threadIdx.x; idx < total; idx += 512 * 512) {
            int t = idx;
            if (t < NE) { E16[t] = f2bf(E[t]); continue; }
            t -= NE;
            if (t < NW0) {
                int k = t >> 9, f = t & 511;
                W0cT[f * 256 + k] = f2bf(Wsc0[(512 + k) * 512 + f]);
                continue;
            }
            t -= NW0;
            if (t < NCAT) {
                int e = t & 127, k = (t >> 7) & 255, r = (t >> 15) & 3, d = (t >> 17) & 1, l = t >> 18;
                const float* src = (d == 0) ? Wfw : Wbw;
                float v = src[((l * 4 + r) * 256 + k) * 128 + e];
                WcatT[(l * 1024 + d * 512 + r * 128 + e) * 256 + k] = f2bf(v);
                continue;
            }
            t -= NCAT;
            if (t < NLIN) {
                int d = t & 255, f = (t >> 8) & 255, l = t >> 16;
                WlinT[(l * 256 + d) * 256 + f] = f2bf(Wlin[(l * 256 + f) * 256 + d]);
                continue;
            }
            t -= NLIN;
            {
                int f = t & 255, l = t >> 8;
                float s = 0.f;
                if (f < 128) { for (int r = 0; r < 4; ++r) s += bbw[(l * 4 + r) * 128 + f]; }
                else         { for (int r = 0; r < 4; ++r) s += bfw[(l * 4 + r) * 128 + (f - 128)]; }
                bsumS[l * 256 + f] = s;
            }
        }
    } else {
        int j0 = (blockIdx.x - 512) * 8;
        int tid = threadIdx.x;
        for (int t = tid; t < 2048; t += 512) sE[t >> 8][t & 255] = E[j0 * 256 + t];
        __syncthreads();
        int f = tid;
        float u[8] = {0,0,0,0,0,0,0,0}, v[8] = {0,0,0,0,0,0,0,0};
        for (int k = 0; k < 256; ++k) {
            float wa = Wsc0[k * 512 + f];
            float wb = Wsc0[(256 + k) * 512 + f];
#pragma unroll
            for (int jj = 0; jj < 8; ++jj) { u[jj] += sE[jj][k] * wa; v[jj] += sE[jj][k] * wb; }
        }
        float b0f = bsc0[f];
#pragma unroll
        for (int jj = 0; jj < 8; ++jj) {
            U[(j0 + jj) * 512 + f] = u[jj] + b0f;   // fold b0 into U
            V[(j0 + jj) * 512 + f] = v[jj];
        }
    }
}

// ---------------- pair scorer ----------------
__global__ __launch_bounds__(512) void pair_kernel(
    const float* __restrict__ E, const unsigned short* __restrict__ W0cT,
    const float* __restrict__ U, const float* __restrict__ V,
    const float* __restrict__ W1, const float* __restrict__ b1,
    unsigned short* __restrict__ A16) {

    __shared__ unsigned short prodL[64 * 256];   // 32 KB XOR-swizzled
    __shared__ float partial[64 * 4 * 33];       // 33 KB
    __shared__ float scoresL[64 * 4];

    const int i = blockIdx.x;
    const int j0 = blockIdx.y * 64;
    const int tid = threadIdx.x;
    const int lane = tid & 63;
    const int w = tid >> 6;
    const int l15 = lane & 15, l4 = lane >> 4;

    // acc init = U'(=U+b0)[j][f] + V[i][f]  (loads issued early, overlap staging)
    float Vv[4];
#pragma unroll
    for (int nb = 0; nb < 4; ++nb) Vv[nb] = V[i * 512 + w * 64 + nb * 16 + l15];
    f32x4 acc[4][4];
#pragma unroll
    for (int mb = 0; mb < 4; ++mb)
#pragma unroll
        for (int reg = 0; reg < 4; ++reg) {
            const float* Urow = U + (j0 + mb * 16 + l4 * 4 + reg) * 512 + w * 64 + l15;
#pragma unroll
            for (int nb = 0; nb < 4; ++nb)
                acc[mb][nb][reg] = Urow[nb * 16] + Vv[nb];
        }

    // stage product tile (64 j-rows x 256 k) as bf16, coalesced reads
    {
        int m = tid >> 3;
        const float4* ej = (const float4*)(E + (j0 + m) * 256);
        const float4* ei = (const float4*)(E + i * 256);
        char* base = (char*)prodL;
#pragma unroll
        for (int c = 0; c < 8; ++c) {
            int q = (tid & 7) + c * 8;           // float4 index within row
            float4 a = ej[q], b = ei[q];
            uint2 val;
            val.x = pack2bf(a.x * b.x, a.y * b.y);
            val.y = pack2bf(a.z * b.z, a.w * b.w);
            int byteoff = m * 512 + (((q * 8)) ^ ((m & 7) << 4));   // q*4 floats -> q*8 bytes
            *(uint2*)(base + byteoff) = val;
        }
    }
    __syncthreads();

    const char* pbase = (const char*)prodL;
    for (int kk = 0; kk < 8; ++kk) {
        bf16x8 afr[4], bfr[4];
#pragma unroll
        for (int mb = 0; mb < 4; ++mb) {
            int row = mb * 16 + l15;
            int off = row * 512 + ((kk * 64 + l4 * 16) ^ ((row & 7) << 4));
            afr[mb] = *(const bf16x8*)(pbase + off);
        }
#pragma unroll
        for (int nb = 0; nb < 4; ++nb) {
            int fcol = w * 64 + nb * 16 + l15;
            bfr[nb] = *(const bf16x8*)(W0cT + fcol * 256 + kk * 32 + l4 * 8);
        }
#pragma unroll
        for (int mb = 0; mb < 4; ++mb)
#pragma unroll
            for (int nb = 0; nb < 4; ++nb)
                acc[mb][nb] = __builtin_amdgcn_mfma_f32_16x16x32_bf16(afr[mb], bfr[nb], acc[mb][nb], 0, 0, 0);
    }

    // epilogue: h = relu(acc); partial scores = h @ W_sc1
    float4 w1v[4];
#pragma unroll
    for (int nb = 0; nb < 4; ++nb) w1v[nb] = *(const float4*)(W1 + (w * 64 + nb * 16 + l15) * 4);
#pragma unroll
    for (int mb = 0; mb < 4; ++mb) {
        float s2[4][4];
#pragma unroll
        for (int reg = 0; reg < 4; ++reg) {
            s2[reg][0] = 0.f; s2[reg][1] = 0.f; s2[reg][2] = 0.f; s2[reg][3] = 0.f;
#pragma unroll
            for (int nb = 0; nb < 4; ++nb) {
                float h = fmaxf(acc[mb][nb][reg], 0.f);
                s2[reg][0] += h * w1v[nb].x;
                s2[reg][1] += h * w1v[nb].y;
                s2[reg][2] += h * w1v[nb].z;
                s2[reg][3] += h * w1v[nb].w;
            }
        }
#pragma unroll
        for (int reg = 0; reg < 4; ++reg)
#pragma unroll
            for (int r = 0; r < 4; ++r) {
                float vs = s2[reg][r];
                vs += __shfl_xor(vs, 1);
                vs += __shfl_xor(vs, 2);
                s2[reg][r] = vs;
            }
        if ((lane & 3) == 0) {
            int slot = w * 4 + ((lane & 15) >> 2);
#pragma unroll
            for (int reg = 0; reg < 4; ++reg) {
                int m = mb * 16 + l4 * 4 + reg;
#pragma unroll
                for (int r = 0; r < 4; ++r) partial[(m * 4 + r) * 33 + slot] = s2[reg][r];
            }
        }
    }
    __syncthreads();
    if (tid < 256) {
        int m = tid >> 2, r = tid & 3;
        float sc = b1[r];
#pragma unroll
        for (int p = 0; p < 32; ++p) sc += partial[(m * 4 + r) * 33 + p];
        scoresL[m * 4 + r] = sc;
    }
    __syncthreads();
    if (tid < 64) {
        int m = tid, j = j0 + m;
        float s0 = scoresL[m * 4 + 0], s1 = scoresL[m * 4 + 1];
        float sA = scoresL[m * 4 + 2], sB = scoresL[m * 4 + 3];
        float mx = fmaxf(fmaxf(s0, s1), fmaxf(sA, sB));
        float e0 = __expf(s0 - mx), e1 = __expf(s1 - mx), e2 = __expf(sA - mx), e3 = __expf(sB - mx);
        float inv = 1.f / (e0 + e1 + e2 + e3);
        float p_[4] = {e0 * inv, e1 * inv, e2 * inv, e3 * inv};
        if (j == i) { p_[0] = p_[1] = p_[2] = p_[3] = 0.f; }
#pragma unroll
        for (int r = 0; r < 4; ++r)
            A16[(r * 512 + i) * 512 + j] = f2bf(p_[r]);   // coalesced rows only
    }
}

// ---------------- panel helpers: 32-row full-K LDS panels, XOR-swizzled ----------------
template<int K>
__device__ __forceinline__ void stageP(unsigned short* lds, const unsigned short* g, int ldg, int tid) {
    constexpr int SLOTS = K / 8;
#pragma unroll
    for (int it = 0; it < (32 * SLOTS) / 256; ++it) {
        int u = it * 256 + tid;
        int row = u / SLOTS, slot = u % SLOTS;
        uint4 v = *(const uint4*)(g + row * ldg + slot * 8);
        *(uint4*)((char*)lds + row * (K * 2) + ((slot * 16) ^ ((row & 7) << 4))) = v;
    }
}
template<int K>
__device__ __forceinline__ bf16x8 fragP(const unsigned short* lds, int row, int kc, int l4) {
    return *(const bf16x8*)((const char*)lds + row * (K * 2) + ((((kc * 4 + l4) * 16) ^ ((row & 7) << 4))));
}

// ---------------- c1: supT[c][j] = WcatT[c][:] . x16[j][:]  (+ fused A->AT transpose blocks) ----------------
__global__ __launch_bounds__(256) void c1_kernel(const unsigned short* __restrict__ WcatT,
                                                 const unsigned short* __restrict__ x16,
                                                 unsigned short* __restrict__ supT,
                                                 const unsigned short* __restrict__ A16,
                                                 unsigned short* __restrict__ AT16, int l) {
    __shared__ unsigned short lA[32 * 256], lB[32 * 256];
    int tid = threadIdx.x;
    if (blockIdx.y >= 16) {
        // transpose job: AT16[r][x][y] = A16[r][y][x], 64x64 tiles
        auto t = (unsigned short(*)[65])lA;
        int job = (blockIdx.y - 16) * 32 + blockIdx.x;  // 0..255
        int r = job >> 6, ty = (job >> 3) & 7, tx = job & 7;
        const unsigned short* src = A16 + (r * 512 + ty * 64) * 512 + tx * 64;
        unsigned short* dst = AT16 + (r * 512 + tx * 64) * 512 + ty * 64;
#pragma unroll
        for (int it = 0; it < 2; ++it) {
            int u = it * 256 + tid, row = u >> 3, c8 = (u & 7) * 8;
            uint4 v = *(const uint4*)(src + row * 512 + c8);
            const unsigned short* p = (const unsigned short*)&v;
#pragma unroll
            for (int e = 0; e < 8; ++e) t[c8 + e][row] = p[e];
        }
        __syncthreads();
#pragma unroll
        for (int it = 0; it < 2; ++it) {
            int u = it * 256 + tid, row = u >> 3, c8 = (u & 7) * 8;
            uint4 v; unsigned short* p = (unsigned short*)&v;
#pragma unroll
            for (int e = 0; e < 8; ++e) p[e] = t[row][c8 + e];
            *(uint4*)(dst + row * 512 + c8) = v;
        }
        return;
    }
    int c0 = blockIdx.x * 32, jt0 = blockIdx.y * 32;
    int lane = tid & 63, w = tid >> 6;
    int wr = (w >> 1) * 16, wc = (w & 1) * 16;
    int l15 = lane & 15, l4 = lane >> 4;
    stageP<256>(lA, WcatT + l * 262144 + c0 * 256, 256, tid);
    stageP<256>(lB, x16 + jt0 * 256, 256, tid);
    __syncthreads();
    f32x4 a0 = {0.f,0.f,0.f,0.f}, a1 = {0.f,0.f,0.f,0.f};
#pragma unroll
    for (int kc = 0; kc < 8; kc += 2) {
        a0 = __builtin_amdgcn_mfma_f32_16x16x32_bf16(fragP<256>(lA, wr + l15, kc, l4),
                                                     fragP<256>(lB, wc + l15, kc, l4), a0, 0, 0, 0);
        a1 = __builtin_amdgcn_mfma_f32_16x16x32_bf16(fragP<256>(lA, wr + l15, kc + 1, l4),
                                                     fragP<256>(lB, wc + l15, kc + 1, l4), a1, 0, 0, 0);
    }
    f32x4 acc = a0 + a1;
#pragma unroll
    for (int reg = 0; reg < 4; ++reg) {
        int c = c0 + wr + l4 * 4 + reg;
        int j = jt0 + wc + l15;
        supT[c * 512 + j] = f2bf(acc[reg]);
    }
}

// ---------------- c2: relS[i][f] = relu(sum_r (A|AT)[r] @ sup[r] + bsum) ----------------
__global__ __launch_bounds__(256) void c2_kernel(const unsigned short* __restrict__ A16,
                                                 const unsigned short* __restrict__ AT16,
                                                 const unsigned short* __restrict__ supT,
                                                 const float* __restrict__ bsumS,
                                                 unsigned short* __restrict__ relS, int l) {
    __shared__ unsigned short lA[32 * 512], lB[32 * 512];
    int i0 = blockIdx.x * 32, f0 = blockIdx.y * 32;
    bool bw = (f0 < 128);
    const unsigned short* Am = bw ? AT16 : A16;
    int e0 = bw ? f0 : (f0 - 128);
    int tid = threadIdx.x, lane = tid & 63, w = tid >> 6;
    int wr = (w >> 1) * 16, wc = (w & 1) * 16;
    int l15 = lane & 15, l4 = lane >> 4;
    f32x4 a0 = {0.f,0.f,0.f,0.f}, a1 = {0.f,0.f,0.f,0.f};
    for (int r = 0; r < 4; ++r) {
        if (r) __syncthreads();
        stageP<512>(lA, Am + (r * 512 + i0) * 512, 512, tid);
        stageP<512>(lB, supT + ((bw ? 512 : 0) + r * 128 + e0) * 512, 512, tid);
        __syncthreads();
#pragma unroll
        for (int kc = 0; kc < 16; kc += 2) {
            a0 = __builtin_amdgcn_mfma_f32_16x16x32_bf16(fragP<512>(lA, wr + l15, kc, l4),
                                                         fragP<512>(lB, wc + l15, kc, l4), a0, 0, 0, 0);
            a1 = __builtin_amdgcn_mfma_f32_16x16x32_bf16(fragP<512>(lA, wr + l15, kc + 1, l4),
                                                         fragP<512>(lB, wc + l15, kc + 1, l4), a1, 0, 0, 0);
        }
    }
    f32x4 acc = a0 + a1;
#pragma unroll
    for (int reg = 0; reg < 4; ++reg) {
        int ii = i0 + wr + l4 * 4 + reg;
        int f = f0 + wc + l15;
        relS[ii * 256 + f] = f2bf(fmaxf(acc[reg] + bsumS[l * 256 + f], 0.f));
    }
}

// ---------------- c3: xnew = relS @ Wlin + blin + xold ----------------
__global__ __launch_bounds__(256) void c3_kernel(const unsigned short* __restrict__ relS,
                                                 const unsigned short* __restrict__ WlinT,
                                                 const float* __restrict__ blin,
                                                 const float* __restrict__ xold,
                                                 float* __restrict__ xnew,
                                                 unsigned short* __restrict__ x16out, int l) {
    __shared__ unsigned short lA[32 * 256], lB[32 * 256];
    int i0 = blockIdx.x * 32, d0 = blockIdx.y * 32;
    int tid = threadIdx.x, lane = tid & 63, w = tid >> 6;
    int wr = (w >> 1) * 16, wc = (w & 1) * 16;
    int l15 = lane & 15, l4 = lane >> 4;
    stageP<256>(lA, relS + i0 * 256, 256, tid);
    stageP<256>(lB, WlinT + l * 65536 + d0 * 256, 256, tid);
    __syncthreads();
    f32x4 a0 = {0.f,0.f,0.f,0.f}, a1 = {0.f,0.f,0.f,0.f};
#pragma unroll
    for (int kc = 0; kc < 8; kc += 2) {
        a0 = __builtin_amdgcn_mfma_f32_16x16x32_bf16(fragP<256>(lA, wr + l15, kc, l4),
                                                     fragP<256>(lB, wc + l15, kc, l4), a0, 0, 0, 0);
        a1 = __builtin_amdgcn_mfma_f32_16x16x32_bf16(fragP<256>(lA, wr + l15, kc + 1, l4),
                                                     fragP<256>(lB, wc + l15, kc + 1, l4), a1, 0, 0, 0);
    }
    f32x4 acc = a0 + a1;
#pragma unroll
    for (int reg = 0; reg < 4; ++reg) {
        int ii = i0 + wr + l4 * 4 + reg;
        int dd = d0 + wc + l15;
        float vv = acc[reg] + blin[l * 256 + dd] + xold[ii * 256 + dd];
        xnew[ii * 256 + dd] = vv;
        x16out[ii * 256 + dd] = f2bf(vv);
    }
}

extern "C" void kernel_launch(void* const* d_in, const int* in_sizes, int n_in,
                              void* d_out, int out_size, void* d_ws, size_t ws_size,
                              hipStream_t stream) {
    const float* E    = (const float*)d_in[0];
    const float* Wsc0 = (const float*)d_in[1];
    const float* bsc0 = (const float*)d_in[2];
    const float* Wsc1 = (const float*)d_in[3];
    const float* bsc1 = (const float*)d_in[4];
    const float* Wfw  = (const float*)d_in[5];
    const float* bfw  = (const float*)d_in[6];
    const float* Wbw  = (const float*)d_in[7];
    const float* bbw  = (const float*)d_in[8];
    const float* Wlin = (const float*)d_in[9];
    const float* blin = (const float*)d_in[10];
    float* out = (float*)d_out;

    char* ws = (char*)d_ws;
    size_t off = 0;
    unsigned short* E16   = (unsigned short*)(ws + off); off += 512 * 256 * 2;
    unsigned short* W0cT  = (unsigned short*)(ws + off); off += 512 * 256 * 2;
    unsigned short* WcatT = (unsigned short*)(ws + off); off += 2 * 1024 * 256 * 2;
    unsigned short* WlinT = (unsigned short*)(ws + off); off += 2 * 256 * 256 * 2;
    float* bsumS          = (float*)(ws + off);          off += 2 * 256 * 4;
    float* U              = (float*)(ws + off);          off += 512 * 512 * 4;
    float* V              = (float*)(ws + off);          off += 512 * 512 * 4;
    unsigned short* A16   = (unsigned short*)(ws + off); off += 4 * 512 * 512 * 2;
    unsigned short* AT16  = (unsigned short*)(ws + off); off += 4 * 512 * 512 * 2;
    unsigned short* supT  = (unsigned short*)(ws + off); off += 1024 * 512 * 2;
    unsigned short* relS  = (unsigned short*)(ws + off); off += 512 * 256 * 2;
    float* xf1            = (float*)(ws + off);          off += 512 * 256 * 4;
    unsigned short* x16_1 = (unsigned short*)(ws + off); off += 512 * 256 * 2;

    prep_uv_kernel<<<576, 512, 0, stream>>>(E, Wsc0, bsc0, Wfw, bfw, Wbw, bbw, Wlin,
                                            E16, W0cT, WcatT, WlinT, bsumS, U, V);
    pair_kernel<<<dim3(512, 8), 512, 0, stream>>>(E, W0cT, U, V, Wsc1, bsc1, A16);

    for (int l = 0; l < 2; ++l) {
        const unsigned short* xin16 = (l == 0) ? E16 : x16_1;
        const float* xoldf = (l == 0) ? E : xf1;
        float* xout = (l == 0) ? xf1 : out;
        c1_kernel<<<dim3(32, (l == 0) ? 24 : 16), 256, 0, stream>>>(WcatT, xin16, supT, A16, AT16, l);
        c2_kernel<<<dim3(16, 8), 256, 0, stream>>>(A16, AT16, supT, bsumS, relS, l);
        c3_kernel<<<dim3(16, 8), 256, 0, stream>>>(relS, WlinT, blin, xoldf, xout, x16_1, l);
    }
    (void)in_sizes; (void)n_in; (void)out_size; (void)ws_size;
}

// Round 3
// 223.875 us; speedup vs baseline: 1.5472x; 1.3520x over previous
//
#include <hip/hip_runtime.h>
#include <hip/hip_bf16.h>

using f32x4  = __attribute__((ext_vector_type(4))) float;
using bf16x8 = __attribute__((ext_vector_type(8))) short;

__device__ __forceinline__ unsigned short f2bf(float f) {
    union { __hip_bfloat16 h; unsigned short u; } cv;
    cv.h = __float2bfloat16(f);
    return cv.u;
}
__device__ __forceinline__ unsigned int pack2bf(float lo, float hi) {
    float2 t; t.x = lo; t.y = hi;
    union { __hip_bfloat162 h; unsigned int u; } cv;
    cv.h = __float22bfloat162_rn(t);
    return cv.u;
}

// ---------------- prep (blocks 0..511) + uv (blocks 512..575) fat kernel ----------------
// W0p packed: elem(e) of lane for (w,nb,kk): fcol=w*64+nb*16+(lane&15), k=kk*32+(lane>>4)*8+e
//   W0p[(((w*4+nb)*8+kk)*64+lane)*8+e]
// Upk packed (b0 folded): for (j,f): j0b=j>>6,w=f>>6,mb=(j>>4)&3,nb=(f>>4)&3,lane=((j>>2)&3)*16+(f&15),reg=j&3
//   Upk[((((j0b*8+w)*4+mb)*4+nb)*64+lane)*4+reg]
__global__ __launch_bounds__(512) void prep_uv_kernel(
        const float* __restrict__ E, const float* __restrict__ Wsc0, const float* __restrict__ bsc0,
        const float* __restrict__ Wfw, const float* __restrict__ bfw,
        const float* __restrict__ Wbw, const float* __restrict__ bbw,
        const float* __restrict__ Wlin,
        unsigned short* __restrict__ E16, unsigned short* __restrict__ W0p,
        unsigned short* __restrict__ WcatT, unsigned short* __restrict__ WlinT,
        float* __restrict__ bsumS, float* __restrict__ Upk, float* __restrict__ V) {
    __shared__ float sE[8][256];
    if (blockIdx.x < 512) {
        const int NE = 131072, NW0 = 131072, NCAT = 524288, NLIN = 131072;
        const int total = NE + NW0 + NCAT + NLIN + 512;
        for (int idx = blockIdx.x * 512 + threadIdx.x; idx < total; idx += 512 * 512) {
            int t = idx;
            if (t < NE) { E16[t] = f2bf(E[t]); continue; }
            t -= NE;
            if (t < NW0) {
                int e = t & 7, lane = (t >> 3) & 63, kk = (t >> 9) & 7, nb = (t >> 12) & 3, w = (t >> 14) & 7;
                int fcol = w * 64 + nb * 16 + (lane & 15);
                int k = kk * 32 + (lane >> 4) * 8 + e;
                W0p[t] = f2bf(Wsc0[(512 + k) * 512 + fcol]);
                continue;
            }
            t -= NW0;
            if (t < NCAT) {
                int e = t & 127, k = (t >> 7) & 255, r = (t >> 15) & 3, d = (t >> 17) & 1, l = t >> 18;
                const float* src = (d == 0) ? Wfw : Wbw;
                float v = src[((l * 4 + r) * 256 + k) * 128 + e];
                WcatT[(l * 1024 + d * 512 + r * 128 + e) * 256 + k] = f2bf(v);
                continue;
            }
            t -= NCAT;
            if (t < NLIN) {
                int d = t & 255, f = (t >> 8) & 255, l = t >> 16;
                WlinT[(l * 256 + d) * 256 + f] = f2bf(Wlin[(l * 256 + f) * 256 + d]);
                continue;
            }
            t -= NLIN;
            {
                int f = t & 255, l = t >> 8;
                float s = 0.f;
                if (f < 128) { for (int r = 0; r < 4; ++r) s += bbw[(l * 4 + r) * 128 + f]; }
                else         { for (int r = 0; r < 4; ++r) s += bfw[(l * 4 + r) * 128 + (f - 128)]; }
                bsumS[l * 256 + f] = s;
            }
        }
    } else {
        int j0 = (blockIdx.x - 512) * 8;
        int tid = threadIdx.x;
        for (int t = tid; t < 2048; t += 512) sE[t >> 8][t & 255] = E[j0 * 256 + t];
        __syncthreads();
        int f = tid;
        float u[8] = {0,0,0,0,0,0,0,0}, v[8] = {0,0,0,0,0,0,0,0};
        for (int k = 0; k < 256; ++k) {
            float wa = Wsc0[k * 512 + f];
            float wb = Wsc0[(256 + k) * 512 + f];
#pragma unroll
            for (int jj = 0; jj < 8; ++jj) { u[jj] += sE[jj][k] * wa; v[jj] += sE[jj][k] * wb; }
        }
        float b0f = bsc0[f];
        int w = f >> 6, nb = (f >> 4) & 3, l15 = f & 15;
#pragma unroll
        for (int jj = 0; jj < 8; ++jj) {
            int j = j0 + jj;
            int j0b = j >> 6, mb = (j >> 4) & 3, lane = ((j >> 2) & 3) * 16 + l15, reg = j & 3;
            Upk[((((j0b * 8 + w) * 4 + mb) * 4 + nb) * 64 + lane) * 4 + reg] = u[jj] + b0f;
            V[j * 512 + f] = v[jj];
        }
    }
}

// ---------------- pair scorer ----------------
__global__ __launch_bounds__(512, 4) void pair_kernel(
    const float* __restrict__ E, const unsigned short* __restrict__ W0p,
    const float* __restrict__ Upk, const float* __restrict__ V,
    const float* __restrict__ W1, const float* __restrict__ b1,
    unsigned short* __restrict__ A16) {

    __shared__ unsigned short prodL[64 * 256];   // 32 KB XOR-swizzled
    __shared__ float partial2[64 * 36];          // 9 KB: [j][r*9+w]
    __shared__ float scoresL[64 * 4];

    const int i = blockIdx.x;
    const int j0b = blockIdx.y;
    const int j0 = j0b * 64;
    const int tid = threadIdx.x;
    const int lane = tid & 63;
    const int w = tid >> 6;
    const int l15 = lane & 15, l4 = lane >> 4;

    // acc init = Upk(=U+b0) + V : coalesced float4 loads, issued before staging
    float Vv[4];
#pragma unroll
    for (int nb = 0; nb < 4; ++nb) Vv[nb] = V[i * 512 + w * 64 + nb * 16 + l15];
    const float4* Up4 = (const float4*)Upk;
    f32x4 acc[4][4];
#pragma unroll
    for (int mb = 0; mb < 4; ++mb)
#pragma unroll
        for (int nb = 0; nb < 4; ++nb) {
            float4 uv_ = Up4[(((j0b * 8 + w) * 4 + mb) * 4 + nb) * 64 + lane];
            acc[mb][nb][0] = uv_.x + Vv[nb];
            acc[mb][nb][1] = uv_.y + Vv[nb];
            acc[mb][nb][2] = uv_.z + Vv[nb];
            acc[mb][nb][3] = uv_.w + Vv[nb];
        }

    // stage product tile (64 j-rows x 256 k) as bf16
    {
        int m = tid >> 3;
        const float4* ej = (const float4*)(E + (j0 + m) * 256);
        const float4* ei = (const float4*)(E + i * 256);
        char* base = (char*)prodL;
#pragma unroll
        for (int c = 0; c < 8; ++c) {
            int q = (tid & 7) + c * 8;
            float4 a = ej[q], b = ei[q];
            uint2 val;
            val.x = pack2bf(a.x * b.x, a.y * b.y);
            val.y = pack2bf(a.z * b.z, a.w * b.w);
            int byteoff = m * 512 + ((q * 8) ^ ((m & 7) << 4));
            *(uint2*)(base + byteoff) = val;
        }
    }
    __syncthreads();

    const char* pbase = (const char*)prodL;
    const bf16x8* Wp8 = (const bf16x8*)W0p;
#pragma unroll
    for (int kk = 0; kk < 8; ++kk) {
        bf16x8 afr[4], bfr[4];
#pragma unroll
        for (int mb = 0; mb < 4; ++mb) {
            int row = mb * 16 + l15;
            int off = row * 512 + ((kk * 64 + l4 * 16) ^ ((row & 7) << 4));
            afr[mb] = *(const bf16x8*)(pbase + off);
        }
#pragma unroll
        for (int nb = 0; nb < 4; ++nb)
            bfr[nb] = Wp8[((w * 4 + nb) * 8 + kk) * 64 + lane];   // coalesced 1KB
#pragma unroll
        for (int mb = 0; mb < 4; ++mb)
#pragma unroll
            for (int nb = 0; nb < 4; ++nb)
                acc[mb][nb] = __builtin_amdgcn_mfma_f32_16x16x32_bf16(afr[mb], bfr[nb], acc[mb][nb], 0, 0, 0);
    }

    // epilogue: h = relu(acc); scores = h @ W_sc1, full in-wave butterfly over l15
    float4 w1v[4];
#pragma unroll
    for (int nb = 0; nb < 4; ++nb) w1v[nb] = *(const float4*)(W1 + (w * 64 + nb * 16 + l15) * 4);
#pragma unroll
    for (int mb = 0; mb < 4; ++mb) {
        float s2[4][4];
#pragma unroll
        for (int reg = 0; reg < 4; ++reg) {
            s2[reg][0] = 0.f; s2[reg][1] = 0.f; s2[reg][2] = 0.f; s2[reg][3] = 0.f;
#pragma unroll
            for (int nb = 0; nb < 4; ++nb) {
                float h = fmaxf(acc[mb][nb][reg], 0.f);
                s2[reg][0] += h * w1v[nb].x;
                s2[reg][1] += h * w1v[nb].y;
                s2[reg][2] += h * w1v[nb].z;
                s2[reg][3] += h * w1v[nb].w;
            }
        }
#pragma unroll
        for (int reg = 0; reg < 4; ++reg)
#pragma unroll
            for (int r = 0; r < 4; ++r) {
                float vs = s2[reg][r];
                vs += __shfl_xor(vs, 1);
                vs += __shfl_xor(vs, 2);
                vs += __shfl_xor(vs, 4);
                vs += __shfl_xor(vs, 8);
                s2[reg][r] = vs;
            }
#pragma unroll
        for (int reg = 0; reg < 4; ++reg)
#pragma unroll
            for (int r = 0; r < 4; ++r)
                if (l15 == r)
                    partial2[(mb * 16 + l4 * 4 + reg) * 36 + r * 9 + w] = s2[reg][r];
    }
    __syncthreads();
    if (tid < 256) {
        int m = tid >> 2, r = tid & 3;
        float sc = b1[r];
#pragma unroll
        for (int p = 0; p < 8; ++p) sc += partial2[m * 36 + r * 9 + p];
        scoresL[m * 4 + r] = sc;
    }
    __syncthreads();
    if (tid < 64) {
        int m = tid, j = j0 + m;
        float s0 = scoresL[m * 4 + 0], s1 = scoresL[m * 4 + 1];
        float sA = scoresL[m * 4 + 2], sB = scoresL[m * 4 + 3];
        float mx = fmaxf(fmaxf(s0, s1), fmaxf(sA, sB));
        float e0 = __expf(s0 - mx), e1 = __expf(s1 - mx), e2 = __expf(sA - mx), e3 = __expf(sB - mx);
        float inv = 1.f / (e0 + e1 + e2 + e3);
        float p_[4] = {e0 * inv, e1 * inv, e2 * inv, e3 * inv};
        if (j == i) { p_[0] = p_[1] = p_[2] = p_[3] = 0.f; }
#pragma unroll
        for (int r = 0; r < 4; ++r)
            A16[(r * 512 + i) * 512 + j] = f2bf(p_[r]);
    }
}

// ---------------- panel helpers: 32-row full-K LDS panels, XOR-swizzled ----------------
template<int K>
__device__ __forceinline__ void stageP(unsigned short* lds, const unsigned short* g, int ldg, int tid) {
    constexpr int SLOTS = K / 8;
#pragma unroll
    for (int it = 0; it < (32 * SLOTS) / 256; ++it) {
        int u = it * 256 + tid;
        int row = u / SLOTS, slot = u % SLOTS;
        uint4 v = *(const uint4*)(g + row * ldg + slot * 8);
        *(uint4*)((char*)lds + row * (K * 2) + ((slot * 16) ^ ((row & 7) << 4))) = v;
    }
}
template<int K>
__device__ __forceinline__ bf16x8 fragP(const unsigned short* lds, int row, int kc, int l4) {
    return *(const bf16x8*)((const char*)lds + row * (K * 2) + ((((kc * 4 + l4) * 16) ^ ((row & 7) << 4))));
}

// ---------------- c1: supT[c][j] = WcatT[c][:] . x16[j][:]  (+ fused A->AT transpose blocks) ----------------
__global__ __launch_bounds__(256) void c1_kernel(const unsigned short* __restrict__ WcatT,
                                                 const unsigned short* __restrict__ x16,
                                                 unsigned short* __restrict__ supT,
                                                 const unsigned short* __restrict__ A16,
                                                 unsigned short* __restrict__ AT16, int l) {
    __shared__ unsigned short lA[32 * 256], lB[32 * 256];
    int tid = threadIdx.x;
    if (blockIdx.y >= 16) {
        auto t = (unsigned short(*)[65])lA;
        int job = (blockIdx.y - 16) * 32 + blockIdx.x;  // 0..255
        int r = job >> 6, ty = (job >> 3) & 7, tx = job & 7;
        const unsigned short* src = A16 + (r * 512 + ty * 64) * 512 + tx * 64;
        unsigned short* dst = AT16 + (r * 512 + tx * 64) * 512 + ty * 64;
#pragma unroll
        for (int it = 0; it < 2; ++it) {
            int u = it * 256 + tid, row = u >> 3, c8 = (u & 7) * 8;
            uint4 v = *(const uint4*)(src + row * 512 + c8);
            const unsigned short* p = (const unsigned short*)&v;
#pragma unroll
            for (int e = 0; e < 8; ++e) t[c8 + e][row] = p[e];
        }
        __syncthreads();
#pragma unroll
        for (int it = 0; it < 2; ++it) {
            int u = it * 256 + tid, row = u >> 3, c8 = (u & 7) * 8;
            uint4 v; unsigned short* p = (unsigned short*)&v;
#pragma unroll
            for (int e = 0; e < 8; ++e) p[e] = t[row][c8 + e];
            *(uint4*)(dst + row * 512 + c8) = v;
        }
        return;
    }
    int c0 = blockIdx.x * 32, jt0 = blockIdx.y * 32;
    int lane = tid & 63, w = tid >> 6;
    int wr = (w >> 1) * 16, wc = (w & 1) * 16;
    int l15 = lane & 15, l4 = lane >> 4;
    stageP<256>(lA, WcatT + l * 262144 + c0 * 256, 256, tid);
    stageP<256>(lB, x16 + jt0 * 256, 256, tid);
    __syncthreads();
    f32x4 a0 = {0.f,0.f,0.f,0.f}, a1 = {0.f,0.f,0.f,0.f};
#pragma unroll
    for (int kc = 0; kc < 8; kc += 2) {
        a0 = __builtin_amdgcn_mfma_f32_16x16x32_bf16(fragP<256>(lA, wr + l15, kc, l4),
                                                     fragP<256>(lB, wc + l15, kc, l4), a0, 0, 0, 0);
        a1 = __builtin_amdgcn_mfma_f32_16x16x32_bf16(fragP<256>(lA, wr + l15, kc + 1, l4),
                                                     fragP<256>(lB, wc + l15, kc + 1, l4), a1, 0, 0, 0);
    }
    f32x4 acc = a0 + a1;
#pragma unroll
    for (int reg = 0; reg < 4; ++reg) {
        int c = c0 + wr + l4 * 4 + reg;
        int j = jt0 + wc + l15;
        supT[c * 512 + j] = f2bf(acc[reg]);
    }
}

// ---------------- c2: relS[i][f] = relu(sum_r (A|AT)[r] @ sup[r] + bsum) ----------------
__global__ __launch_bounds__(256) void c2_kernel(const unsigned short* __restrict__ A16,
                                                 const unsigned short* __restrict__ AT16,
                                                 const unsigned short* __restrict__ supT,
                                                 const float* __restrict__ bsumS,
                                                 unsigned short* __restrict__ relS, int l) {
    __shared__ unsigned short lA[32 * 512], lB[32 * 512];
    int i0 = blockIdx.x * 32, f0 = blockIdx.y * 32;
    bool bw = (f0 < 128);
    const unsigned short* Am = bw ? AT16 : A16;
    int e0 = bw ? f0 : (f0 - 128);
    int tid = threadIdx.x, lane = tid & 63, w = tid >> 6;
    int wr = (w >> 1) * 16, wc = (w & 1) * 16;
    int l15 = lane & 15, l4 = lane >> 4;
    f32x4 a0 = {0.f,0.f,0.f,0.f}, a1 = {0.f,0.f,0.f,0.f};
    for (int r = 0; r < 4; ++r) {
        if (r) __syncthreads();
        stageP<512>(lA, Am + (r * 512 + i0) * 512, 512, tid);
        stageP<512>(lB, supT + ((bw ? 512 : 0) + r * 128 + e0) * 512, 512, tid);
        __syncthreads();
#pragma unroll
        for (int kc = 0; kc < 16; kc += 2) {
            a0 = __builtin_amdgcn_mfma_f32_16x16x32_bf16(fragP<512>(lA, wr + l15, kc, l4),
                                                         fragP<512>(lB, wc + l15, kc, l4), a0, 0, 0, 0);
            a1 = __builtin_amdgcn_mfma_f32_16x16x32_bf16(fragP<512>(lA, wr + l15, kc + 1, l4),
                                                         fragP<512>(lB, wc + l15, kc + 1, l4), a1, 0, 0, 0);
        }
    }
    f32x4 acc = a0 + a1;
#pragma unroll
    for (int reg = 0; reg < 4; ++reg) {
        int ii = i0 + wr + l4 * 4 + reg;
        int f = f0 + wc + l15;
        relS[ii * 256 + f] = f2bf(fmaxf(acc[reg] + bsumS[l * 256 + f], 0.f));
    }
}

// ---------------- c3: xnew = relS @ Wlin + blin + xold ----------------
__global__ __launch_bounds__(256) void c3_kernel(const unsigned short* __restrict__ relS,
                                                 const unsigned short* __restrict__ WlinT,
                                                 const float* __restrict__ blin,
                                                 const float* __restrict__ xold,
                                                 float* __restrict__ xnew,
                                                 unsigned short* __restrict__ x16out, int l) {
    __shared__ unsigned short lA[32 * 256], lB[32 * 256];
    int i0 = blockIdx.x * 32, d0 = blockIdx.y * 32;
    int tid = threadIdx.x, lane = tid & 63, w = tid >> 6;
    int wr = (w >> 1) * 16, wc = (w & 1) * 16;
    int l15 = lane & 15, l4 = lane >> 4;
    stageP<256>(lA, relS + i0 * 256, 256, tid);
    stageP<256>(lB, WlinT + l * 65536 + d0 * 256, 256, tid);
    __syncthreads();
    f32x4 a0 = {0.f,0.f,0.f,0.f}, a1 = {0.f,0.f,0.f,0.f};
#pragma unroll
    for (int kc = 0; kc < 8; kc += 2) {
        a0 = __builtin_amdgcn_mfma_f32_16x16x32_bf16(fragP<256>(lA, wr + l15, kc, l4),
                                                     fragP<256>(lB, wc + l15, kc, l4), a0, 0, 0, 0);
        a1 = __builtin_amdgcn_mfma_f32_16x16x32_bf16(fragP<256>(lA, wr + l15, kc + 1, l4),
                                                     fragP<256>(lB, wc + l15, kc + 1, l4), a1, 0, 0, 0);
    }
    f32x4 acc = a0 + a1;
#pragma unroll
    for (int reg = 0; reg < 4; ++reg) {
        int ii = i0 + wr + l4 * 4 + reg;
        int dd = d0 + wc + l15;
        float vv = acc[reg] + blin[l * 256 + dd] + xold[ii * 256 + dd];
        xnew[ii * 256 + dd] = vv;
        x16out[ii * 256 + dd] = f2bf(vv);
    }
}

extern "C" void kernel_launch(void* const* d_in, const int* in_sizes, int n_in,
                              void* d_out, int out_size, void* d_ws, size_t ws_size,
                              hipStream_t stream) {
    const float* E    = (const float*)d_in[0];
    const float* Wsc0 = (const float*)d_in[1];
    const float* bsc0 = (const float*)d_in[2];
    const float* Wsc1 = (const float*)d_in[3];
    const float* bsc1 = (const float*)d_in[4];
    const float* Wfw  = (const float*)d_in[5];
    const float* bfw  = (const float*)d_in[6];
    const float* Wbw  = (const float*)d_in[7];
    const float* bbw  = (const float*)d_in[8];
    const float* Wlin = (const float*)d_in[9];
    const float* blin = (const float*)d_in[10];
    float* out = (float*)d_out;

    char* ws = (char*)d_ws;
    size_t off = 0;
    unsigned short* E16   = (unsigned short*)(ws + off); off += 512 * 256 * 2;
    unsigned short* W0p   = (unsigned short*)(ws + off); off += 512 * 256 * 2;
    unsigned short* WcatT = (unsigned short*)(ws + off); off += 2 * 1024 * 256 * 2;
    unsigned short* WlinT = (unsigned short*)(ws + off); off += 2 * 256 * 256 * 2;
    float* bsumS          = (float*)(ws + off);          off += 2 * 256 * 4;
    float* Upk            = (float*)(ws + off);          off += 512 * 512 * 4;
    float* V              = (float*)(ws + off);          off += 512 * 512 * 4;
    unsigned short* A16   = (unsigned short*)(ws + off); off += 4 * 512 * 512 * 2;
    unsigned short* AT16  = (unsigned short*)(ws + off); off += 4 * 512 * 512 * 2;
    unsigned short* supT  = (unsigned short*)(ws + off); off += 1024 * 512 * 2;
    unsigned short* relS  = (unsigned short*)(ws + off); off += 512 * 256 * 2;
    float* xf1            = (float*)(ws + off);          off += 512 * 256 * 4;
    unsigned short* x16_1 = (unsigned short*)(ws + off); off += 512 * 256 * 2;

    prep_uv_kernel<<<576, 512, 0, stream>>>(E, Wsc0, bsc0, Wfw, bfw, Wbw, bbw, Wlin,
                                            E16, W0p, WcatT, WlinT, bsumS, Upk, V);
    pair_kernel<<<dim3(512, 8), 512, 0, stream>>>(E, W0p, Upk, V, Wsc1, bsc1, A16);

    for (int l = 0; l < 2; ++l) {
        const unsigned short* xin16 = (l == 0) ? E16 : x16_1;
        const float* xoldf = (l == 0) ? E : xf1;
        float* xout = (l == 0) ? xf1 : out;
        c1_kernel<<<dim3(32, (l == 0) ? 24 : 16), 256, 0, stream>>>(WcatT, xin16, supT, A16, AT16, l);
        c2_kernel<<<dim3(16, 8), 256, 0, stream>>>(A16, AT16, supT, bsumS, relS, l);
        c3_kernel<<<dim3(16, 8), 256, 0, stream>>>(relS, WlinT, blin, xoldf, xout, x16_1, l);
    }
    (void)in_sizes; (void)n_in; (void)out_size; (void)ws_size;
}

// Round 4
// 212.673 us; speedup vs baseline: 1.6287x; 1.0527x over previous
//
#include <hip/hip_runtime.h>
#include <hip/hip_bf16.h>

using f32x4  = __attribute__((ext_vector_type(4))) float;
using bf16x8 = __attribute__((ext_vector_type(8))) short;

__device__ __forceinline__ unsigned short f2bf(float f) {
    union { __hip_bfloat16 h; unsigned short u; } cv;
    cv.h = __float2bfloat16(f);
    return cv.u;
}
__device__ __forceinline__ unsigned int pack2bf(float lo, float hi) {
    float2 t; t.x = lo; t.y = hi;
    union { __hip_bfloat162 h; unsigned int u; } cv;
    cv.h = __float22bfloat162_rn(t);
    return cv.u;
}
__device__ __forceinline__ float bf2f(unsigned short u) {
    return __uint_as_float((unsigned)u << 16);
}

// ---------------- prep (blocks 0..511) + uv (blocks 512..575) ----------------
// W0p:  [(w*4+nb)*8+kk][lane][8e]  fcol=w*64+nb*16+(lane&15), k=kk*32+(lane>>4)*8+e
// Upk (bf16, b0 folded): [jt][w][mb][nb][lane][reg]
// W1p:  [kk][lane][8e]  f=kk*32+(lane>>4)*8+e, col r=lane&15 (0 if r>=4)
__global__ __launch_bounds__(512) void prep_uv_kernel(
        const float* __restrict__ E, const float* __restrict__ Wsc0, const float* __restrict__ bsc0,
        const float* __restrict__ Wsc1,
        const float* __restrict__ Wfw, const float* __restrict__ bfw,
        const float* __restrict__ Wbw, const float* __restrict__ bbw,
        const float* __restrict__ Wlin,
        unsigned short* __restrict__ E16, unsigned short* __restrict__ W0p,
        unsigned short* __restrict__ WcatT, unsigned short* __restrict__ WlinT,
        float* __restrict__ bsumS, unsigned short* __restrict__ Upk,
        float* __restrict__ V, unsigned short* __restrict__ W1p) {
    __shared__ float sE[8][256];
    if (blockIdx.x < 512) {
        const int NE = 131072, NW0 = 131072, NCAT = 524288, NLIN = 131072, NW1P = 8192;
        const int total = NE + NW0 + NCAT + NLIN + NW1P + 512;
        for (int idx = blockIdx.x * 512 + threadIdx.x; idx < total; idx += 512 * 512) {
            int t = idx;
            if (t < NE) { E16[t] = f2bf(E[t]); continue; }
            t -= NE;
            if (t < NW0) {
                int e = t & 7, lane = (t >> 3) & 63, kk = (t >> 9) & 7, nb = (t >> 12) & 3, w = (t >> 14) & 7;
                int fcol = w * 64 + nb * 16 + (lane & 15);
                int k = kk * 32 + (lane >> 4) * 8 + e;
                W0p[t] = f2bf(Wsc0[(512 + k) * 512 + fcol]);
                continue;
            }
            t -= NW0;
            if (t < NCAT) {
                int e = t & 127, k = (t >> 7) & 255, r = (t >> 15) & 3, d = (t >> 17) & 1, l = t >> 18;
                const float* src = (d == 0) ? Wfw : Wbw;
                float v = src[((l * 4 + r) * 256 + k) * 128 + e];
                WcatT[(l * 1024 + d * 512 + r * 128 + e) * 256 + k] = f2bf(v);
                continue;
            }
            t -= NCAT;
            if (t < NLIN) {
                int d = t & 255, f = (t >> 8) & 255, l = t >> 16;
                WlinT[(l * 256 + d) * 256 + f] = f2bf(Wlin[(l * 256 + f) * 256 + d]);
                continue;
            }
            t -= NLIN;
            if (t < NW1P) {
                int e = t & 7, lane = (t >> 3) & 63, kk = t >> 9;
                int f = kk * 32 + (lane >> 4) * 8 + e;
                int r = lane & 15;
                W1p[t] = (r < 4) ? f2bf(Wsc1[f * 4 + r]) : (unsigned short)0;
                continue;
            }
            t -= NW1P;
            {
                int f = t & 255, l = t >> 8;
                float s = 0.f;
                if (f < 128) { for (int r = 0; r < 4; ++r) s += bbw[(l * 4 + r) * 128 + f]; }
                else         { for (int r = 0; r < 4; ++r) s += bfw[(l * 4 + r) * 128 + (f - 128)]; }
                bsumS[l * 256 + f] = s;
            }
        }
    } else {
        int j0 = (blockIdx.x - 512) * 8;
        int tid = threadIdx.x;
        for (int t = tid; t < 2048; t += 512) sE[t >> 8][t & 255] = E[j0 * 256 + t];
        __syncthreads();
        int f = tid;
        float u[8] = {0,0,0,0,0,0,0,0}, v[8] = {0,0,0,0,0,0,0,0};
        for (int k = 0; k < 256; ++k) {
            float wa = Wsc0[k * 512 + f];
            float wb = Wsc0[(256 + k) * 512 + f];
#pragma unroll
            for (int jj = 0; jj < 8; ++jj) { u[jj] += sE[jj][k] * wa; v[jj] += sE[jj][k] * wb; }
        }
        float b0f = bsc0[f];
        int w = f >> 6, nb = (f >> 4) & 3, l15 = f & 15;
#pragma unroll
        for (int jj = 0; jj < 8; ++jj) {
            int j = j0 + jj;
            int jt = j >> 6, mb = (j >> 4) & 3, lane = ((j >> 2) & 3) * 16 + l15, reg = j & 3;
            Upk[(((((jt * 8 + w) * 4 + mb) * 4 + nb) * 64 + lane) * 4 + reg)] = f2bf(u[jj] + b0f);
            V[j * 512 + f] = v[jj];
        }
    }
}

// ---------------- pair scorer: MFMA main + MFMA score-reduce ----------------
__global__ __launch_bounds__(512, 3) void pair_kernel(
    const float* __restrict__ E, const unsigned short* __restrict__ W0p,
    const unsigned short* __restrict__ Upk, const float* __restrict__ V,
    const unsigned short* __restrict__ W1p, const float* __restrict__ b1,
    unsigned short* __restrict__ A16) {

    __shared__ unsigned short prodL[64 * 256];   // 32 KB; reused as H (32 rows x 512 f) in epilogue
    __shared__ float Spart[8 * 64 * 5];          // 10 KB
    __shared__ float scoresL[64 * 4];

    const int i = blockIdx.x;
    const int jt = blockIdx.y;
    const int j0 = jt * 64;
    const int tid = threadIdx.x;
    const int lane = tid & 63;
    const int w = tid >> 6;
    const int l15 = lane & 15, l4 = lane >> 4;

    // acc init = Upk(bf16, U+b0) + V
    float Vv[4];
#pragma unroll
    for (int nb = 0; nb < 4; ++nb) Vv[nb] = V[i * 512 + w * 64 + nb * 16 + l15];
    f32x4 acc[4][4];
#pragma unroll
    for (int mb = 0; mb < 4; ++mb)
#pragma unroll
        for (int nb = 0; nb < 4; ++nb) {
            int idx4 = (((jt * 8 + w) * 4 + mb) * 4 + nb) * 64 + lane;
            ushort4 uq = ((const ushort4*)Upk)[idx4];
            acc[mb][nb][0] = bf2f(uq.x) + Vv[nb];
            acc[mb][nb][1] = bf2f(uq.y) + Vv[nb];
            acc[mb][nb][2] = bf2f(uq.z) + Vv[nb];
            acc[mb][nb][3] = bf2f(uq.w) + Vv[nb];
        }

    // stage product tile (64 j x 256 k) bf16, XOR-swizzled
    {
        int m = tid >> 3;
        const float4* ej = (const float4*)(E + (j0 + m) * 256);
        const float4* ei = (const float4*)(E + i * 256);
        char* base = (char*)prodL;
#pragma unroll
        for (int c = 0; c < 8; ++c) {
            int q = (tid & 7) + c * 8;
            float4 a = ej[q], b = ei[q];
            uint2 val;
            val.x = pack2bf(a.x * b.x, a.y * b.y);
            val.y = pack2bf(a.z * b.z, a.w * b.w);
            int byteoff = m * 512 + ((q * 8) ^ ((m & 7) << 4));
            *(uint2*)(base + byteoff) = val;
        }
    }
    __syncthreads();

    const char* pbase = (const char*)prodL;
    const bf16x8* Wp8 = (const bf16x8*)W0p;
#pragma unroll
    for (int kk = 0; kk < 8; ++kk) {
        bf16x8 afr[4], bfr[4];
#pragma unroll
        for (int mb = 0; mb < 4; ++mb) {
            int row = mb * 16 + l15;
            int off = row * 512 + ((kk * 64 + l4 * 16) ^ ((row & 7) << 4));
            afr[mb] = *(const bf16x8*)(pbase + off);
        }
#pragma unroll
        for (int nb = 0; nb < 4; ++nb)
            bfr[nb] = Wp8[((w * 4 + nb) * 8 + kk) * 64 + lane];
#pragma unroll
        for (int mb = 0; mb < 4; ++mb)
#pragma unroll
            for (int nb = 0; nb < 4; ++nb)
                acc[mb][nb] = __builtin_amdgcn_mfma_f32_16x16x32_bf16(afr[mb], bfr[nb], acc[mb][nb], 0, 0, 0);
    }

    // ---- epilogue: H = relu(acc) -> bf16 LDS (2 passes of 32 rows), S = H @ W1p via MFMA ----
    __syncthreads();    // prodL reads complete; safe to overlay H
    char* hb = (char*)prodL;
    const bf16x8* W1p8 = (const bf16x8*)W1p;
    f32x4 accS[4];
#pragma unroll
    for (int q = 0; q < 4; ++q) accS[q] = (f32x4){0.f, 0.f, 0.f, 0.f};

#pragma unroll
    for (int p = 0; p < 2; ++p) {
        // write H rows [32p, 32p+32): from acc mb = 2p, 2p+1
#pragma unroll
        for (int mbl = 0; mbl < 2; ++mbl) {
#pragma unroll
            for (int nb = 0; nb < 4; ++nb) {
                int col = w * 64 + nb * 16 + l15;
#pragma unroll
                for (int reg = 0; reg < 4; ++reg) {
                    int rl = mbl * 16 + l4 * 4 + reg;
                    float hv = fmaxf(acc[p * 2 + mbl][nb][reg], 0.f);
                    *(unsigned short*)(hb + rl * 1024 + ((col * 2) ^ ((rl & 7) << 4))) = f2bf(hv);
                }
            }
        }
        __syncthreads();
        // S-MFMA: wave w reduces f in [64w, 64w+64) for these 32 rows
#pragma unroll
        for (int mbl = 0; mbl < 2; ++mbl) {
            int rl = mbl * 16 + l15;
#pragma unroll
            for (int kkl = 0; kkl < 2; ++kkl) {
                int kk = w * 2 + kkl;
                bf16x8 ha = *(const bf16x8*)(hb + rl * 1024 + ((kk * 64 + l4 * 16) ^ ((rl & 7) << 4)));
                accS[p * 2 + mbl] = __builtin_amdgcn_mfma_f32_16x16x32_bf16(ha, W1p8[kk * 64 + lane], accS[p * 2 + mbl], 0, 0, 0);
            }
        }
        __syncthreads();
    }

    // scatter per-wave partial scores (cols l15<4 hold r)
    if (l15 < 4) {
#pragma unroll
        for (int q = 0; q < 4; ++q)
#pragma unroll
            for (int reg = 0; reg < 4; ++reg)
                Spart[(w * 64 + q * 16 + l4 * 4 + reg) * 5 + l15] = accS[q][reg];
    }
    __syncthreads();
    if (tid < 256) {
        int m = tid >> 2, r = tid & 3;
        float sc = b1[r];
#pragma unroll
        for (int p8 = 0; p8 < 8; ++p8) sc += Spart[(p8 * 64 + m) * 5 + r];
        scoresL[m * 4 + r] = sc;
    }
    __syncthreads();
    if (tid < 64) {
        int m = tid, j = j0 + m;
        float s0 = scoresL[m * 4 + 0], s1 = scoresL[m * 4 + 1];
        float sA = scoresL[m * 4 + 2], sB = scoresL[m * 4 + 3];
        float mx = fmaxf(fmaxf(s0, s1), fmaxf(sA, sB));
        float e0 = __expf(s0 - mx), e1 = __expf(s1 - mx), e2 = __expf(sA - mx), e3 = __expf(sB - mx);
        float inv = 1.f / (e0 + e1 + e2 + e3);
        float p_[4] = {e0 * inv, e1 * inv, e2 * inv, e3 * inv};
        if (j == i) { p_[0] = p_[1] = p_[2] = p_[3] = 0.f; }
#pragma unroll
        for (int r = 0; r < 4; ++r)
            A16[(r * 512 + i) * 512 + j] = f2bf(p_[r]);
    }
}

// ---------------- LDS panel helpers ----------------
template<int K>
__device__ __forceinline__ void stageP(unsigned short* lds, const unsigned short* g, int ldg, int tid) {
    constexpr int SLOTS = K / 8;
#pragma unroll
    for (int it = 0; it < (32 * SLOTS) / 256; ++it) {
        int u = it * 256 + tid;
        int row = u / SLOTS, slot = u % SLOTS;
        uint4 v = *(const uint4*)(g + row * ldg + slot * 8);
        *(uint4*)((char*)lds + row * (K * 2) + ((slot * 16) ^ ((row & 7) << 4))) = v;
    }
}
__device__ __forceinline__ void stage64(unsigned short* lds, const unsigned short* g, int ldg, int tid) {
#pragma unroll
    for (int it = 0; it < 8; ++it) {
        int u = it * 256 + tid;
        int row = u >> 5, slot = u & 31;
        uint4 v = *(const uint4*)(g + row * ldg + slot * 8);
        *(uint4*)((char*)lds + row * 512 + ((slot * 16) ^ ((row & 7) << 4))) = v;
    }
}
template<int K>
__device__ __forceinline__ bf16x8 fragP(const unsigned short* lds, int row, int kc, int l4) {
    return *(const bf16x8*)((const char*)lds + row * (K * 2) + ((((kc * 4 + l4) * 16) ^ ((row & 7) << 4))));
}

// ---------------- c1: supT = WcatT . x16^T  (+ fused A->AT transpose jobs, l=0) ----------------
__global__ __launch_bounds__(256) void c1_kernel(const unsigned short* __restrict__ WcatT,
                                                 const unsigned short* __restrict__ x16,
                                                 unsigned short* __restrict__ supT,
                                                 const unsigned short* __restrict__ A16,
                                                 unsigned short* __restrict__ AT16, int l) {
    __shared__ unsigned short lA[32 * 256], lB[32 * 256];
    int tid = threadIdx.x;
    if (blockIdx.y >= 16) {
        auto t = (unsigned short(*)[65])lA;
        int job = (blockIdx.y - 16) * 32 + blockIdx.x;
        int r = job >> 6, ty = (job >> 3) & 7, tx = job & 7;
        const unsigned short* src = A16 + (r * 512 + ty * 64) * 512 + tx * 64;
        unsigned short* dst = AT16 + (r * 512 + tx * 64) * 512 + ty * 64;
#pragma unroll
        for (int it = 0; it < 2; ++it) {
            int u = it * 256 + tid, row = u >> 3, c8 = (u & 7) * 8;
            uint4 v = *(const uint4*)(src + row * 512 + c8);
            const unsigned short* p = (const unsigned short*)&v;
#pragma unroll
            for (int e = 0; e < 8; ++e) t[c8 + e][row] = p[e];
        }
        __syncthreads();
#pragma unroll
        for (int it = 0; it < 2; ++it) {
            int u = it * 256 + tid, row = u >> 3, c8 = (u & 7) * 8;
            uint4 v; unsigned short* p = (unsigned short*)&v;
#pragma unroll
            for (int e = 0; e < 8; ++e) p[e] = t[row][c8 + e];
            *(uint4*)(dst + row * 512 + c8) = v;
        }
        return;
    }
    int c0 = blockIdx.x * 32, jt0 = blockIdx.y * 32;
    int lane = tid & 63, w = tid >> 6;
    int wr = (w >> 1) * 16, wc = (w & 1) * 16;
    int l15 = lane & 15, l4 = lane >> 4;
    stageP<256>(lA, WcatT + l * 262144 + c0 * 256, 256, tid);
    stageP<256>(lB, x16 + jt0 * 256, 256, tid);
    __syncthreads();
    f32x4 a0 = {0.f,0.f,0.f,0.f}, a1 = {0.f,0.f,0.f,0.f};
#pragma unroll
    for (int kc = 0; kc < 8; kc += 2) {
        a0 = __builtin_amdgcn_mfma_f32_16x16x32_bf16(fragP<256>(lA, wr + l15, kc, l4),
                                                     fragP<256>(lB, wc + l15, kc, l4), a0, 0, 0, 0);
        a1 = __builtin_amdgcn_mfma_f32_16x16x32_bf16(fragP<256>(lA, wr + l15, kc + 1, l4),
                                                     fragP<256>(lB, wc + l15, kc + 1, l4), a1, 0, 0, 0);
    }
    f32x4 acc = a0 + a1;
#pragma unroll
    for (int reg = 0; reg < 4; ++reg) {
        int c = c0 + wr + l4 * 4 + reg;
        int j = jt0 + wc + l15;
        supT[c * 512 + j] = f2bf(acc[reg]);
    }
}

// ---------------- c2 (split-k): Pc2[s] = partial (A|AT)[r] @ sup[r], 64x64 tiles, K=256 ----------------
__global__ __launch_bounds__(256) void c2_kernel(const unsigned short* __restrict__ A16,
                                                 const unsigned short* __restrict__ AT16,
                                                 const unsigned short* __restrict__ supT,
                                                 float* __restrict__ Pc2) {
    __shared__ unsigned short lA[64 * 256], lB[64 * 256];
    int i0 = blockIdx.x * 64, f0 = blockIdx.y * 64;
    int s = blockIdx.z, r = s >> 1, kh = s & 1;
    bool bw = (f0 < 128);
    int e0 = bw ? f0 : (f0 - 128);
    const unsigned short* Am = bw ? AT16 : A16;
    int tid = threadIdx.x, lane = tid & 63, w = tid >> 6;
    int wr = (w >> 1) * 32, wc = (w & 1) * 32;
    int l15 = lane & 15, l4 = lane >> 4;
    stage64(lA, Am + (r * 512 + i0) * 512 + kh * 256, 512, tid);
    stage64(lB, supT + ((bw ? 512 : 0) + r * 128 + e0) * 512 + kh * 256, 512, tid);
    __syncthreads();
    f32x4 acc[2][2];
#pragma unroll
    for (int a_ = 0; a_ < 2; ++a_)
#pragma unroll
        for (int b_ = 0; b_ < 2; ++b_) acc[a_][b_] = (f32x4){0.f, 0.f, 0.f, 0.f};
#pragma unroll
    for (int kc = 0; kc < 8; ++kc) {
        bf16x8 af[2], bf_[2];
#pragma unroll
        for (int mb = 0; mb < 2; ++mb) af[mb] = fragP<256>(lA, wr + mb * 16 + l15, kc, l4);
#pragma unroll
        for (int nb = 0; nb < 2; ++nb) bf_[nb] = fragP<256>(lB, wc + nb * 16 + l15, kc, l4);
#pragma unroll
        for (int mb = 0; mb < 2; ++mb)
#pragma unroll
            for (int nb = 0; nb < 2; ++nb)
                acc[mb][nb] = __builtin_amdgcn_mfma_f32_16x16x32_bf16(af[mb], bf_[nb], acc[mb][nb], 0, 0, 0);
    }
    float* dst = Pc2 + s * 131072;
#pragma unroll
    for (int mb = 0; mb < 2; ++mb)
#pragma unroll
        for (int nb = 0; nb < 2; ++nb)
#pragma unroll
            for (int reg = 0; reg < 4; ++reg)
                dst[(i0 + wr + mb * 16 + l4 * 4 + reg) * 256 + f0 + wc + nb * 16 + l15] = acc[mb][nb][reg];
}

// ---------------- c3: xnew = relu(sum_s Pc2 + bsum) @ Wlin + blin + xold ----------------
__global__ __launch_bounds__(256) void c3_kernel(const float* __restrict__ Pc2,
                                                 const float* __restrict__ bsumS,
                                                 const unsigned short* __restrict__ WlinT,
                                                 const float* __restrict__ blin,
                                                 const float* __restrict__ xold,
                                                 float* __restrict__ xnew,
                                                 unsigned short* __restrict__ x16out, int l) {
    __shared__ unsigned short lA[32 * 256], lB[32 * 256];
    int i0 = blockIdx.x * 32, d0 = blockIdx.y * 32;
    int tid = threadIdx.x, lane = tid & 63, w = tid >> 6;
    int wr = (w >> 1) * 16, wc = (w & 1) * 16;
    int l15 = lane & 15, l4 = lane >> 4;
    // stage A: combine 8 partials + bias + relu -> bf16
#pragma unroll
    for (int g = 0; g < 4; ++g) {
        int u = g * 256 + tid;
        int row = u >> 5, k8 = (u & 31) * 8;
        float s[8] = {0,0,0,0,0,0,0,0};
#pragma unroll
        for (int s8 = 0; s8 < 8; ++s8) {
            const float4* p = (const float4*)(Pc2 + s8 * 131072 + (i0 + row) * 256 + k8);
            float4 a = p[0], b = p[1];
            s[0] += a.x; s[1] += a.y; s[2] += a.z; s[3] += a.w;
            s[4] += b.x; s[5] += b.y; s[6] += b.z; s[7] += b.w;
        }
        uint4 v;
        unsigned* vp = (unsigned*)&v;
#pragma unroll
        for (int e2 = 0; e2 < 4; ++e2) {
            float lo = fmaxf(s[e2 * 2] + bsumS[l * 256 + k8 + e2 * 2], 0.f);
            float hi = fmaxf(s[e2 * 2 + 1] + bsumS[l * 256 + k8 + e2 * 2 + 1], 0.f);
            vp[e2] = pack2bf(lo, hi);
        }
        *(uint4*)((char*)lA + row * 512 + ((k8 * 2) ^ ((row & 7) << 4))) = v;
    }
    stageP<256>(lB, WlinT + l * 65536 + d0 * 256, 256, tid);
    __syncthreads();
    f32x4 a0 = {0.f,0.f,0.f,0.f}, a1 = {0.f,0.f,0.f,0.f};
#pragma unroll
    for (int kc = 0; kc < 8; kc += 2) {
        a0 = __builtin_amdgcn_mfma_f32_16x16x32_bf16(fragP<256>(lA, wr + l15, kc, l4),
                                                     fragP<256>(lB, wc + l15, kc, l4), a0, 0, 0, 0);
        a1 = __builtin_amdgcn_mfma_f32_16x16x32_bf16(fragP<256>(lA, wr + l15, kc + 1, l4),
                                                     fragP<256>(lB, wc + l15, kc + 1, l4), a1, 0, 0, 0);
    }
    f32x4 acc = a0 + a1;
#pragma unroll
    for (int reg = 0; reg < 4; ++reg) {
        int ii = i0 + wr + l4 * 4 + reg;
        int dd = d0 + wc + l15;
        float vv = acc[reg] + blin[l * 256 + dd] + xold[ii * 256 + dd];
        xnew[ii * 256 + dd] = vv;
        x16out[ii * 256 + dd] = f2bf(vv);
    }
}

extern "C" void kernel_launch(void* const* d_in, const int* in_sizes, int n_in,
                              void* d_out, int out_size, void* d_ws, size_t ws_size,
                              hipStream_t stream) {
    const float* E    = (const float*)d_in[0];
    const float* Wsc0 = (const float*)d_in[1];
    const float* bsc0 = (const float*)d_in[2];
    const float* Wsc1 = (const float*)d_in[3];
    const float* bsc1 = (const float*)d_in[4];
    const float* Wfw  = (const float*)d_in[5];
    const float* bfw  = (const float*)d_in[6];
    const float* Wbw  = (const float*)d_in[7];
    const float* bbw  = (const float*)d_in[8];
    const float* Wlin = (const float*)d_in[9];
    const float* blin = (const float*)d_in[10];
    float* out = (float*)d_out;

    char* ws = (char*)d_ws;
    size_t off = 0;
    unsigned short* E16   = (unsigned short*)(ws + off); off += 512 * 256 * 2;        // 256 KB
    unsigned short* W0p   = (unsigned short*)(ws + off); off += 512 * 256 * 2;        // 256 KB
    unsigned short* WcatT = (unsigned short*)(ws + off); off += 2 * 1024 * 256 * 2;   // 1 MB
    unsigned short* WlinT = (unsigned short*)(ws + off); off += 2 * 256 * 256 * 2;    // 256 KB
    float* bsumS          = (float*)(ws + off);          off += 2 * 256 * 4;          // 2 KB
    unsigned short* Upk   = (unsigned short*)(ws + off); off += 512 * 512 * 2;        // 512 KB
    float* V              = (float*)(ws + off);          off += 512 * 512 * 4;        // 1 MB
    unsigned short* W1p   = (unsigned short*)(ws + off); off += 16 * 64 * 8 * 2;      // 16 KB
    unsigned short* A16   = (unsigned short*)(ws + off); off += 4 * 512 * 512 * 2;    // 2 MB
    unsigned short* AT16  = (unsigned short*)(ws + off); off += 4 * 512 * 512 * 2;    // 2 MB
    unsigned short* supT  = (unsigned short*)(ws + off); off += 1024 * 512 * 2;       // 1 MB
    float* Pc2            = (float*)(ws + off);          off += 8 * 512 * 256 * 4;    // 4 MB
    float* xf1            = (float*)(ws + off);          off += 512 * 256 * 4;        // 512 KB
    unsigned short* x16_1 = (unsigned short*)(ws + off); off += 512 * 256 * 2;        // 256 KB

    prep_uv_kernel<<<576, 512, 0, stream>>>(E, Wsc0, bsc0, Wsc1, Wfw, bfw, Wbw, bbw, Wlin,
                                            E16, W0p, WcatT, WlinT, bsumS, Upk, V, W1p);
    pair_kernel<<<dim3(512, 8), 512, 0, stream>>>(E, W0p, Upk, V, W1p, bsc1, A16);

    for (int l = 0; l < 2; ++l) {
        const unsigned short* xin16 = (l == 0) ? E16 : x16_1;
        const float* xoldf = (l == 0) ? E : xf1;
        float* xout = (l == 0) ? xf1 : out;
        c1_kernel<<<dim3(32, (l == 0) ? 24 : 16), 256, 0, stream>>>(WcatT, xin16, supT, A16, AT16, l);
        c2_kernel<<<dim3(8, 4, 8), 256, 0, stream>>>(A16, AT16, supT, Pc2);
        c3_kernel<<<dim3(16, 8), 256, 0, stream>>>(Pc2, bsumS, WlinT, blin, xoldf, xout, x16_1, l);
    }
    (void)in_sizes; (void)n_in; (void)out_size; (void)ws_size;
}

// Round 5
// 199.591 us; speedup vs baseline: 1.7355x; 1.0655x over previous
//
#include <hip/hip_runtime.h>
#include <hip/hip_bf16.h>

using f32x4  = __attribute__((ext_vector_type(4))) float;
using bf16x8 = __attribute__((ext_vector_type(8))) short;

__device__ __forceinline__ unsigned short f2bf(float f) {
    union { __hip_bfloat16 h; unsigned short u; } cv;
    cv.h = __float2bfloat16(f);
    return cv.u;
}
__device__ __forceinline__ unsigned int pack2bf(float lo, float hi) {
    float2 t; t.x = lo; t.y = hi;
    union { __hip_bfloat162 h; unsigned int u; } cv;
    cv.h = __float22bfloat162_rn(t);
    return cv.u;
}
__device__ __forceinline__ float bf2f(unsigned short u) {
    return __uint_as_float((unsigned)u << 16);
}

// ---------------- prep: converts / packs ----------------
// W0p  : [(w*4+nb)*8+kk][lane][8e]   fcol=w*64+nb*16+(lane&15), k=kk*32+(lane>>4)*8+e
// WabP : [(wf*4+nb)*8+kk][lane][8e]  fcol=wf*64+nb*16+(lane&15) in [0,1024), same k
// W1p  : [kap][lane][8e]  f'=kap*32+(lane>>4)*8+e, r=lane&15 (0 if r>=4); f' permuted:
//        f' = w*64 + q*4 + nb  <->  f = w*64 + nb*16 + q
__global__ __launch_bounds__(512) void prep_kernel(
        const float* __restrict__ E, const float* __restrict__ Wsc0, const float* __restrict__ Wsc1,
        const float* __restrict__ Wfw, const float* __restrict__ bfw,
        const float* __restrict__ Wbw, const float* __restrict__ bbw,
        const float* __restrict__ Wlin,
        unsigned short* __restrict__ E16, unsigned short* __restrict__ W0p,
        unsigned short* __restrict__ WabP,
        unsigned short* __restrict__ WcatT, unsigned short* __restrict__ WlinT,
        float* __restrict__ bsumS, unsigned short* __restrict__ W1p) {
    const int NE = 131072, NW0 = 131072, NWAB = 262144, NCAT = 524288, NLIN = 131072, NW1P = 8192;
    const int total = NE + NW0 + NWAB + NCAT + NLIN + NW1P + 512;
    for (int idx = blockIdx.x * 512 + threadIdx.x; idx < total; idx += 512 * 512) {
        int t = idx;
        if (t < NE) { E16[t] = f2bf(E[t]); continue; }
        t -= NE;
        if (t < NW0) {
            int e = t & 7, lane = (t >> 3) & 63, kk = (t >> 9) & 7, nb = (t >> 12) & 3, w = (t >> 14) & 7;
            int fcol = w * 64 + nb * 16 + (lane & 15);
            int k = kk * 32 + (lane >> 4) * 8 + e;
            W0p[t] = f2bf(Wsc0[(512 + k) * 512 + fcol]);
            continue;
        }
        t -= NW0;
        if (t < NWAB) {
            int e = t & 7, lane = (t >> 3) & 63, kk = (t >> 9) & 7, nb = (t >> 12) & 3, wf = t >> 14;
            int fcol = wf * 64 + nb * 16 + (lane & 15);      // 0..1023
            int k = kk * 32 + (lane >> 4) * 8 + e;
            int row = (fcol < 512) ? k : (256 + k);
            WabP[t] = f2bf(Wsc0[row * 512 + (fcol & 511)]);
            continue;
        }
        t -= NWAB;
        if (t < NCAT) {
            int e = t & 127, k = (t >> 7) & 255, r = (t >> 15) & 3, d = (t >> 17) & 1, l = t >> 18;
            const float* src = (d == 0) ? Wfw : Wbw;
            float v = src[((l * 4 + r) * 256 + k) * 128 + e];
            WcatT[(l * 1024 + d * 512 + r * 128 + e) * 256 + k] = f2bf(v);
            continue;
        }
        t -= NCAT;
        if (t < NLIN) {
            int d = t & 255, f = (t >> 8) & 255, l = t >> 16;
            WlinT[(l * 256 + d) * 256 + f] = f2bf(Wlin[(l * 256 + f) * 256 + d]);
            continue;
        }
        t -= NLIN;
        if (t < NW1P) {
            int e = t & 7, lane = (t >> 3) & 63, kap = t >> 9;
            int fp = kap * 32 + (lane >> 4) * 8 + e;         // f'
            int w = fp >> 6, q = (fp >> 2) & 15, nb = fp & 3;
            int f = w * 64 + nb * 16 + q;                    // inverse permutation
            int r = lane & 15;
            W1p[t] = (r < 4) ? f2bf(Wsc1[f * 4 + r]) : (unsigned short)0;
            continue;
        }
        t -= NW1P;
        {
            int f = t & 255, l = t >> 8;
            float s = 0.f;
            if (f < 128) { for (int r = 0; r < 4; ++r) s += bbw[(l * 4 + r) * 128 + f]; }
            else         { for (int r = 0; r < 4; ++r) s += bfw[(l * 4 + r) * 128 + (f - 128)]; }
            bsumS[l * 256 + f] = s;
        }
    }
}

// ---------------- uv: U=E@W0a (+b0, packed layout), V=E@W0b (transposed bf16) via MFMA ----------------
__global__ __launch_bounds__(512) void uv_kernel(const unsigned short* __restrict__ E16,
                                                 const unsigned short* __restrict__ WabP,
                                                 const float* __restrict__ bsc0,
                                                 unsigned short* __restrict__ Upk,
                                                 unsigned short* __restrict__ VT16) {
    __shared__ unsigned short sE[32 * 256];   // 16 KB swizzled
    const int jt = blockIdx.x;
    const int tid = threadIdx.x, lane = tid & 63, w = tid >> 6;
    const int l15 = lane & 15, l4 = lane >> 4;
#pragma unroll
    for (int it = 0; it < 2; ++it) {
        int u = it * 512 + tid;
        int row = u >> 5, slot = u & 31;
        uint4 v = *(const uint4*)(E16 + (jt * 32 + row) * 256 + slot * 8);
        *(uint4*)((char*)sE + row * 512 + ((slot * 16) ^ ((row & 7) << 4))) = v;
    }
    __syncthreads();
    const bf16x8* Wab8 = (const bf16x8*)WabP;
    f32x4 acc[2][8];
#pragma unroll
    for (int a_ = 0; a_ < 2; ++a_)
#pragma unroll
        for (int b_ = 0; b_ < 8; ++b_) acc[a_][b_] = (f32x4){0.f, 0.f, 0.f, 0.f};
#pragma unroll
    for (int kk = 0; kk < 8; ++kk) {
        bf16x8 af[2];
#pragma unroll
        for (int mbl = 0; mbl < 2; ++mbl) {
            int row = mbl * 16 + l15;
            af[mbl] = *(const bf16x8*)((char*)sE + row * 512 + ((kk * 64 + l4 * 16) ^ ((row & 7) << 4)));
        }
#pragma unroll
        for (int nb = 0; nb < 8; ++nb) {
            int wf = 2 * w + (nb >> 2);
            bf16x8 bfr = Wab8[((wf * 4 + (nb & 3)) * 8 + kk) * 64 + lane];
#pragma unroll
            for (int mbl = 0; mbl < 2; ++mbl)
                acc[mbl][nb] = __builtin_amdgcn_mfma_f32_16x16x32_bf16(af[mbl], bfr, acc[mbl][nb], 0, 0, 0);
        }
    }
#pragma unroll
    for (int mbl = 0; mbl < 2; ++mbl) {
        int j_base = jt * 32 + mbl * 16 + l4 * 4;
#pragma unroll
        for (int nb = 0; nb < 8; ++nb) {
            int f_g = (2 * w + (nb >> 2)) * 64 + (nb & 3) * 16 + l15;
            ushort4 o;
            if (f_g < 512) {
                float b0f = bsc0[f_g];
                o.x = f2bf(acc[mbl][nb][0] + b0f);
                o.y = f2bf(acc[mbl][nb][1] + b0f);
                o.z = f2bf(acc[mbl][nb][2] + b0f);
                o.w = f2bf(acc[mbl][nb][3] + b0f);
                int idx = (((j_base >> 6) * 8 + (f_g >> 6)) * 4 + ((j_base >> 4) & 3)) * 4 + ((f_g >> 4) & 3);
                *(ushort4*)(Upk + (idx * 64 + (l4 * 16 + l15)) * 4) = o;
            } else {
                o.x = f2bf(acc[mbl][nb][0]);
                o.y = f2bf(acc[mbl][nb][1]);
                o.z = f2bf(acc[mbl][nb][2]);
                o.w = f2bf(acc[mbl][nb][3]);
                *(ushort4*)(VT16 + (f_g - 512) * 512 + j_base) = o;
            }
        }
    }
}

// ---------------- pair scorer ----------------
__global__ __launch_bounds__(512) void pair_kernel(
    const float* __restrict__ E, const unsigned short* __restrict__ W0p,
    const unsigned short* __restrict__ Upk, const unsigned short* __restrict__ VT16,
    const unsigned short* __restrict__ W1p, const float* __restrict__ b1,
    unsigned short* __restrict__ A16) {

    __shared__ unsigned short prodL[64 * 256];   // 32 KB; reused as H (32 rows x 512 f') in epilogue
    __shared__ float scoresL[64 * 4];            // 1 KB

    const int i = blockIdx.x;
    const int jt = blockIdx.y;
    const int j0 = jt * 64;
    const int tid = threadIdx.x;
    const int lane = tid & 63;
    const int w = tid >> 6;
    const int l15 = lane & 15, l4 = lane >> 4;

    // acc init = Upk(bf16, U+b0) + V(bf16, transposed)
    float Vv[4];
#pragma unroll
    for (int nb = 0; nb < 4; ++nb) Vv[nb] = bf2f(VT16[(w * 64 + nb * 16 + l15) * 512 + i]);
    f32x4 acc[4][4];
#pragma unroll
    for (int mb = 0; mb < 4; ++mb)
#pragma unroll
        for (int nb = 0; nb < 4; ++nb) {
            int idx4 = (((jt * 8 + w) * 4 + mb) * 4 + nb) * 64 + lane;
            ushort4 uq = ((const ushort4*)Upk)[idx4];
            acc[mb][nb][0] = bf2f(uq.x) + Vv[nb];
            acc[mb][nb][1] = bf2f(uq.y) + Vv[nb];
            acc[mb][nb][2] = bf2f(uq.z) + Vv[nb];
            acc[mb][nb][3] = bf2f(uq.w) + Vv[nb];
        }

    // stage product tile (64 j x 256 k) bf16, XOR-swizzled
    {
        int m = tid >> 3;
        const float4* ej = (const float4*)(E + (j0 + m) * 256);
        const float4* ei = (const float4*)(E + i * 256);
        char* base = (char*)prodL;
#pragma unroll
        for (int c = 0; c < 8; ++c) {
            int q = (tid & 7) + c * 8;
            float4 a = ej[q], b = ei[q];
            uint2 val;
            val.x = pack2bf(a.x * b.x, a.y * b.y);
            val.y = pack2bf(a.z * b.z, a.w * b.w);
            int byteoff = m * 512 + ((q * 8) ^ ((m & 7) << 4));
            *(uint2*)(base + byteoff) = val;
        }
    }
    __syncthreads();

    const char* pbase = (const char*)prodL;
    const bf16x8* Wp8 = (const bf16x8*)W0p;
#pragma unroll
    for (int kk = 0; kk < 8; ++kk) {
        bf16x8 afr[4], bfr[4];
#pragma unroll
        for (int mb = 0; mb < 4; ++mb) {
            int row = mb * 16 + l15;
            int off = row * 512 + ((kk * 64 + l4 * 16) ^ ((row & 7) << 4));
            afr[mb] = *(const bf16x8*)(pbase + off);
        }
#pragma unroll
        for (int nb = 0; nb < 4; ++nb)
            bfr[nb] = Wp8[((w * 4 + nb) * 8 + kk) * 64 + lane];
#pragma unroll
        for (int mb = 0; mb < 4; ++mb)
#pragma unroll
            for (int nb = 0; nb < 4; ++nb)
                acc[mb][nb] = __builtin_amdgcn_mfma_f32_16x16x32_bf16(afr[mb], bfr[nb], acc[mb][nb], 0, 0, 0);
    }

    // ---- epilogue: H' = relu(acc) in f'-permuted order (f' = w*64 + l15*4 + nb), packed b64 writes;
    //      S = H' @ W1p' via MFMA; cross-wave sum via ds_add_f32 ----
    if (tid < 256) scoresL[tid] = b1[tid & 3];
    __syncthreads();   // also guarantees all prodL reads done before overlay

    char* hb = (char*)prodL;
    const bf16x8* W1p8 = (const bf16x8*)W1p;
    bf16x8 w1f[2];
#pragma unroll
    for (int kl = 0; kl < 2; ++kl) w1f[kl] = W1p8[(w * 2 + kl) * 64 + lane];

    f32x4 accS[4];
#pragma unroll
    for (int q = 0; q < 4; ++q) accS[q] = (f32x4){0.f, 0.f, 0.f, 0.f};

#pragma unroll
    for (int p = 0; p < 2; ++p) {
#pragma unroll
        for (int mbl = 0; mbl < 2; ++mbl) {
            int mb = p * 2 + mbl;
#pragma unroll
            for (int reg = 0; reg < 4; ++reg) {
                int rl = mbl * 16 + l4 * 4 + reg;
                float h0 = fmaxf(acc[mb][0][reg], 0.f);
                float h1 = fmaxf(acc[mb][1][reg], 0.f);
                float h2 = fmaxf(acc[mb][2][reg], 0.f);
                float h3 = fmaxf(acc[mb][3][reg], 0.f);
                uint2 val;
                val.x = pack2bf(h0, h1);
                val.y = pack2bf(h2, h3);
                *(uint2*)(hb + rl * 1024 + ((w * 128 + l15 * 8) ^ ((rl & 7) << 4))) = val;
            }
        }
        __syncthreads();
#pragma unroll
        for (int mbl = 0; mbl < 2; ++mbl) {
            int rl = mbl * 16 + l15;
#pragma unroll
            for (int kl = 0; kl < 2; ++kl) {
                bf16x8 ha = *(const bf16x8*)(hb + rl * 1024 + (((w * 2 + kl) * 64 + l4 * 16) ^ ((rl & 7) << 4)));
                accS[p * 2 + mbl] = __builtin_amdgcn_mfma_f32_16x16x32_bf16(ha, w1f[kl], accS[p * 2 + mbl], 0, 0, 0);
            }
        }
        __syncthreads();
    }

    if (l15 < 4) {
#pragma unroll
        for (int q = 0; q < 4; ++q)
#pragma unroll
            for (int reg = 0; reg < 4; ++reg)
                atomicAdd(&scoresL[(q * 16 + l4 * 4 + reg) * 4 + l15], accS[q][reg]);
    }
    __syncthreads();
    if (tid < 64) {
        int m = tid, j = j0 + m;
        float s0 = scoresL[m * 4 + 0], s1 = scoresL[m * 4 + 1];
        float sA = scoresL[m * 4 + 2], sB = scoresL[m * 4 + 3];
        float mx = fmaxf(fmaxf(s0, s1), fmaxf(sA, sB));
        float e0 = __expf(s0 - mx), e1 = __expf(s1 - mx), e2 = __expf(sA - mx), e3 = __expf(sB - mx);
        float inv = 1.f / (e0 + e1 + e2 + e3);
        float p_[4] = {e0 * inv, e1 * inv, e2 * inv, e3 * inv};
        if (j == i) { p_[0] = p_[1] = p_[2] = p_[3] = 0.f; }
#pragma unroll
        for (int r = 0; r < 4; ++r)
            A16[(r * 512 + i) * 512 + j] = f2bf(p_[r]);
    }
}

// ---------------- LDS panel helpers ----------------
template<int K>
__device__ __forceinline__ void stageP(unsigned short* lds, const unsigned short* g, int ldg, int tid) {
    constexpr int SLOTS = K / 8;
#pragma unroll
    for (int it = 0; it < (32 * SLOTS) / 256; ++it) {
        int u = it * 256 + tid;
        int row = u / SLOTS, slot = u % SLOTS;
        uint4 v = *(const uint4*)(g + row * ldg + slot * 8);
        *(uint4*)((char*)lds + row * (K * 2) + ((slot * 16) ^ ((row & 7) << 4))) = v;
    }
}
__device__ __forceinline__ void stage64(unsigned short* lds, const unsigned short* g, int ldg, int tid) {
#pragma unroll
    for (int it = 0; it < 8; ++it) {
        int u = it * 256 + tid;
        int row = u >> 5, slot = u & 31;
        uint4 v = *(const uint4*)(g + row * ldg + slot * 8);
        *(uint4*)((char*)lds + row * 512 + ((slot * 16) ^ ((row & 7) << 4))) = v;
    }
}
template<int K>
__device__ __forceinline__ bf16x8 fragP(const unsigned short* lds, int row, int kc, int l4) {
    return *(const bf16x8*)((const char*)lds + row * (K * 2) + ((((kc * 4 + l4) * 16) ^ ((row & 7) << 4))));
}

// ---------------- c1: supT = WcatT . x16^T  (+ fused A->AT transpose jobs, l=0) ----------------
__global__ __launch_bounds__(256) void c1_kernel(const unsigned short* __restrict__ WcatT,
                                                 const unsigned short* __restrict__ x16,
                                                 unsigned short* __restrict__ supT,
                                                 const unsigned short* __restrict__ A16,
                                                 unsigned short* __restrict__ AT16, int l) {
    __shared__ unsigned short lA[32 * 256], lB[32 * 256];
    int tid = threadIdx.x;
    if (blockIdx.y >= 16) {
        auto t = (unsigned short(*)[65])lA;
        int job = (blockIdx.y - 16) * 32 + blockIdx.x;
        int r = job >> 6, ty = (job >> 3) & 7, tx = job & 7;
        const unsigned short* src = A16 + (r * 512 + ty * 64) * 512 + tx * 64;
        unsigned short* dst = AT16 + (r * 512 + tx * 64) * 512 + ty * 64;
#pragma unroll
        for (int it = 0; it < 2; ++it) {
            int u = it * 256 + tid, row = u >> 3, c8 = (u & 7) * 8;
            uint4 v = *(const uint4*)(src + row * 512 + c8);
            const unsigned short* p = (const unsigned short*)&v;
#pragma unroll
            for (int e = 0; e < 8; ++e) t[c8 + e][row] = p[e];
        }
        __syncthreads();
#pragma unroll
        for (int it = 0; it < 2; ++it) {
            int u = it * 256 + tid, row = u >> 3, c8 = (u & 7) * 8;
            uint4 v; unsigned short* p = (unsigned short*)&v;
#pragma unroll
            for (int e = 0; e < 8; ++e) p[e] = t[row][c8 + e];
            *(uint4*)(dst + row * 512 + c8) = v;
        }
        return;
    }
    int c0 = blockIdx.x * 32, jt0 = blockIdx.y * 32;
    int lane = tid & 63, w = tid >> 6;
    int wr = (w >> 1) * 16, wc = (w & 1) * 16;
    int l15 = lane & 15, l4 = lane >> 4;
    stageP<256>(lA, WcatT + l * 262144 + c0 * 256, 256, tid);
    stageP<256>(lB, x16 + jt0 * 256, 256, tid);
    __syncthreads();
    f32x4 a0 = {0.f,0.f,0.f,0.f}, a1 = {0.f,0.f,0.f,0.f};
#pragma unroll
    for (int kc = 0; kc < 8; kc += 2) {
        a0 = __builtin_amdgcn_mfma_f32_16x16x32_bf16(fragP<256>(lA, wr + l15, kc, l4),
                                                     fragP<256>(lB, wc + l15, kc, l4), a0, 0, 0, 0);
        a1 = __builtin_amdgcn_mfma_f32_16x16x32_bf16(fragP<256>(lA, wr + l15, kc + 1, l4),
                                                     fragP<256>(lB, wc + l15, kc + 1, l4), a1, 0, 0, 0);
    }
    f32x4 acc = a0 + a1;
#pragma unroll
    for (int reg = 0; reg < 4; ++reg) {
        int c = c0 + wr + l4 * 4 + reg;
        int j = jt0 + wc + l15;
        supT[c * 512 + j] = f2bf(acc[reg]);
    }
}

// ---------------- c2 (split-k): Pc2[s] = partial (A|AT)[r] @ sup[r], 64x64 tiles ----------------
__global__ __launch_bounds__(256) void c2_kernel(const unsigned short* __restrict__ A16,
                                                 const unsigned short* __restrict__ AT16,
                                                 const unsigned short* __restrict__ supT,
                                                 float* __restrict__ Pc2) {
    __shared__ unsigned short lA[64 * 256], lB[64 * 256];
    int i0 = blockIdx.x * 64, f0 = blockIdx.y * 64;
    int s = blockIdx.z, r = s >> 1, kh = s & 1;
    bool bw = (f0 < 128);
    int e0 = bw ? f0 : (f0 - 128);
    const unsigned short* Am = bw ? AT16 : A16;
    int tid = threadIdx.x, lane = tid & 63, w = tid >> 6;
    int wr = (w >> 1) * 32, wc = (w & 1) * 32;
    int l15 = lane & 15, l4 = lane >> 4;
    stage64(lA, Am + (r * 512 + i0) * 512 + kh * 256, 512, tid);
    stage64(lB, supT + ((bw ? 512 : 0) + r * 128 + e0) * 512 + kh * 256, 512, tid);
    __syncthreads();
    f32x4 acc[2][2];
#pragma unroll
    for (int a_ = 0; a_ < 2; ++a_)
#pragma unroll
        for (int b_ = 0; b_ < 2; ++b_) acc[a_][b_] = (f32x4){0.f, 0.f, 0.f, 0.f};
#pragma unroll
    for (int kc = 0; kc < 8; ++kc) {
        bf16x8 af[2], bf_[2];
#pragma unroll
        for (int mb = 0; mb < 2; ++mb) af[mb] = fragP<256>(lA, wr + mb * 16 + l15, kc, l4);
#pragma unroll
        for (int nb = 0; nb < 2; ++nb) bf_[nb] = fragP<256>(lB, wc + nb * 16 + l15, kc, l4);
#pragma unroll
        for (int mb = 0; mb < 2; ++mb)
#pragma unroll
            for (int nb = 0; nb < 2; ++nb)
                acc[mb][nb] = __builtin_amdgcn_mfma_f32_16x16x32_bf16(af[mb], bf_[nb], acc[mb][nb], 0, 0, 0);
    }
    float* dst = Pc2 + s * 131072;
#pragma unroll
    for (int mb = 0; mb < 2; ++mb)
#pragma unroll
        for (int nb = 0; nb < 2; ++nb)
#pragma unroll
            for (int reg = 0; reg < 4; ++reg)
                dst[(i0 + wr + mb * 16 + l4 * 4 + reg) * 256 + f0 + wc + nb * 16 + l15] = acc[mb][nb][reg];
}

// ---------------- c3: xnew = relu(sum_s Pc2 + bsum) @ Wlin + blin + xold ----------------
__global__ __launch_bounds__(256) void c3_kernel(const float* __restrict__ Pc2,
                                                 const float* __restrict__ bsumS,
                                                 const unsigned short* __restrict__ WlinT,
                                                 const float* __restrict__ blin,
                                                 const float* __restrict__ xold,
                                                 float* __restrict__ xnew,
                                                 unsigned short* __restrict__ x16out, int l) {
    __shared__ unsigned short lA[32 * 256], lB[32 * 256];
    int i0 = blockIdx.x * 32, d0 = blockIdx.y * 32;
    int tid = threadIdx.x, lane = tid & 63, w = tid >> 6;
    int wr = (w >> 1) * 16, wc = (w & 1) * 16;
    int l15 = lane & 15, l4 = lane >> 4;
#pragma unroll
    for (int g = 0; g < 4; ++g) {
        int u = g * 256 + tid;
        int row = u >> 5, k8 = (u & 31) * 8;
        float s[8] = {0,0,0,0,0,0,0,0};
#pragma unroll
        for (int s8 = 0; s8 < 8; ++s8) {
            const float4* p = (const float4*)(Pc2 + s8 * 131072 + (i0 + row) * 256 + k8);
            float4 a = p[0], b = p[1];
            s[0] += a.x; s[1] += a.y; s[2] += a.z; s[3] += a.w;
            s[4] += b.x; s[5] += b.y; s[6] += b.z; s[7] += b.w;
        }
        uint4 v;
        unsigned* vp = (unsigned*)&v;
#pragma unroll
        for (int e2 = 0; e2 < 4; ++e2) {
            float lo = fmaxf(s[e2 * 2] + bsumS[l * 256 + k8 + e2 * 2], 0.f);
            float hi = fmaxf(s[e2 * 2 + 1] + bsumS[l * 256 + k8 + e2 * 2 + 1], 0.f);
            vp[e2] = pack2bf(lo, hi);
        }
        *(uint4*)((char*)lA + row * 512 + ((k8 * 2) ^ ((row & 7) << 4))) = v;
    }
    stageP<256>(lB, WlinT + l * 65536 + d0 * 256, 256, tid);
    __syncthreads();
    f32x4 a0 = {0.f,0.f,0.f,0.f}, a1 = {0.f,0.f,0.f,0.f};
#pragma unroll
    for (int kc = 0; kc < 8; kc += 2) {
        a0 = __builtin_amdgcn_mfma_f32_16x16x32_bf16(fragP<256>(lA, wr + l15, kc, l4),
                                                     fragP<256>(lB, wc + l15, kc, l4), a0, 0, 0, 0);
        a1 = __builtin_amdgcn_mfma_f32_16x16x32_bf16(fragP<256>(lA, wr + l15, kc + 1, l4),
                                                     fragP<256>(lB, wc + l15, kc + 1, l4), a1, 0, 0, 0);
    }
    f32x4 acc = a0 + a1;
#pragma unroll
    for (int reg = 0; reg < 4; ++reg) {
        int ii = i0 + wr + l4 * 4 + reg;
        int dd = d0 + wc + l15;
        float vv = acc[reg] + blin[l * 256 + dd] + xold[ii * 256 + dd];
        xnew[ii * 256 + dd] = vv;
        x16out[ii * 256 + dd] = f2bf(vv);
    }
}

extern "C" void kernel_launch(void* const* d_in, const int* in_sizes, int n_in,
                              void* d_out, int out_size, void* d_ws, size_t ws_size,
                              hipStream_t stream) {
    const float* E    = (const float*)d_in[0];
    const float* Wsc0 = (const float*)d_in[1];
    const float* bsc0 = (const float*)d_in[2];
    const float* Wsc1 = (const float*)d_in[3];
    const float* bsc1 = (const float*)d_in[4];
    const float* Wfw  = (const float*)d_in[5];
    const float* bfw  = (const float*)d_in[6];
    const float* Wbw  = (const float*)d_in[7];
    const float* bbw  = (const float*)d_in[8];
    const float* Wlin = (const float*)d_in[9];
    const float* blin = (const float*)d_in[10];
    float* out = (float*)d_out;

    char* ws = (char*)d_ws;
    size_t off = 0;
    unsigned short* E16   = (unsigned short*)(ws + off); off += 512 * 256 * 2;        // 256 KB
    unsigned short* W0p   = (unsigned short*)(ws + off); off += 512 * 256 * 2;        // 256 KB
    unsigned short* WabP  = (unsigned short*)(ws + off); off += 1024 * 256 * 2;       // 512 KB
    unsigned short* WcatT = (unsigned short*)(ws + off); off += 2 * 1024 * 256 * 2;   // 1 MB
    unsigned short* WlinT = (unsigned short*)(ws + off); off += 2 * 256 * 256 * 2;    // 256 KB
    float* bsumS          = (float*)(ws + off);          off += 2 * 256 * 4;          // 2 KB
    unsigned short* Upk   = (unsigned short*)(ws + off); off += 512 * 512 * 2;        // 512 KB
    unsigned short* VT16  = (unsigned short*)(ws + off); off += 512 * 512 * 2;        // 512 KB
    unsigned short* W1p   = (unsigned short*)(ws + off); off += 16 * 64 * 8 * 2;      // 16 KB
    unsigned short* A16   = (unsigned short*)(ws + off); off += 4 * 512 * 512 * 2;    // 2 MB
    unsigned short* AT16  = (unsigned short*)(ws + off); off += 4 * 512 * 512 * 2;    // 2 MB
    unsigned short* supT  = (unsigned short*)(ws + off); off += 1024 * 512 * 2;       // 1 MB
    float* Pc2            = (float*)(ws + off);          off += 8 * 512 * 256 * 4;    // 4 MB
    float* xf1            = (float*)(ws + off);          off += 512 * 256 * 4;        // 512 KB
    unsigned short* x16_1 = (unsigned short*)(ws + off); off += 512 * 256 * 2;        // 256 KB

    prep_kernel<<<512, 512, 0, stream>>>(E, Wsc0, Wsc1, Wfw, bfw, Wbw, bbw, Wlin,
                                         E16, W0p, WabP, WcatT, WlinT, bsumS, W1p);
    uv_kernel<<<16, 512, 0, stream>>>(E16, WabP, bsc0, Upk, VT16);
    pair_kernel<<<dim3(512, 8), 512, 0, stream>>>(E, W0p, Upk, VT16, W1p, bsc1, A16);

    for (int l = 0; l < 2; ++l) {
        const unsigned short* xin16 = (l == 0) ? E16 : x16_1;
        const float* xoldf = (l == 0) ? E : xf1;
        float* xout = (l == 0) ? xf1 : out;
        c1_kernel<<<dim3(32, (l == 0) ? 24 : 16), 256, 0, stream>>>(WcatT, xin16, supT, A16, AT16, l);
        c2_kernel<<<dim3(8, 4, 8), 256, 0, stream>>>(A16, AT16, supT, Pc2);
        c3_kernel<<<dim3(16, 8), 256, 0, stream>>>(Pc2, bsumS, WlinT, blin, xoldf, xout, x16_1, l);
    }
    (void)in_sizes; (void)n_in; (void)out_size; (void)ws_size;
}

// Round 6
// 187.344 us; speedup vs baseline: 1.8489x; 1.0654x over previous
//
#include <hip/hip_runtime.h>
#include <hip/hip_bf16.h>

using f32x4  = __attribute__((ext_vector_type(4))) float;
using bf16x8 = __attribute__((ext_vector_type(8))) short;

__device__ __forceinline__ unsigned short f2bf(float f) {
    union { __hip_bfloat16 h; unsigned short u; } cv;
    cv.h = __float2bfloat16(f);
    return cv.u;
}
__device__ __forceinline__ unsigned int pack2bf(float lo, float hi) {
    float2 t; t.x = lo; t.y = hi;
    union { __hip_bfloat162 h; unsigned int u; } cv;
    cv.h = __float22bfloat162_rn(t);
    return cv.u;
}
__device__ __forceinline__ float bf2f(unsigned short u) {
    return __uint_as_float((unsigned)u << 16);
}

// ---------------- prep: converts / packs ----------------
__global__ __launch_bounds__(512) void prep_kernel(
        const float* __restrict__ E, const float* __restrict__ Wsc0, const float* __restrict__ Wsc1,
        const float* __restrict__ Wfw, const float* __restrict__ bfw,
        const float* __restrict__ Wbw, const float* __restrict__ bbw,
        const float* __restrict__ Wlin,
        unsigned short* __restrict__ E16, unsigned short* __restrict__ W0p,
        unsigned short* __restrict__ WabP,
        unsigned short* __restrict__ WcatT, unsigned short* __restrict__ WlinT,
        float* __restrict__ bsumS, unsigned short* __restrict__ W1p) {
    const int NE = 131072, NW0 = 131072, NWAB = 262144, NCAT = 524288, NLIN = 131072, NW1P = 8192;
    const int total = NE + NW0 + NWAB + NCAT + NLIN + NW1P + 512;
    for (int idx = blockIdx.x * 512 + threadIdx.x; idx < total; idx += 512 * 512) {
        int t = idx;
        if (t < NE) { E16[t] = f2bf(E[t]); continue; }
        t -= NE;
        if (t < NW0) {
            int e = t & 7, lane = (t >> 3) & 63, kk = (t >> 9) & 7, nb = (t >> 12) & 3, w = (t >> 14) & 7;
            int fcol = w * 64 + nb * 16 + (lane & 15);
            int k = kk * 32 + (lane >> 4) * 8 + e;
            W0p[t] = f2bf(Wsc0[(512 + k) * 512 + fcol]);
            continue;
        }
        t -= NW0;
        if (t < NWAB) {
            int e = t & 7, lane = (t >> 3) & 63, kk = (t >> 9) & 7, nb = (t >> 12) & 3, wf = t >> 14;
            int fcol = wf * 64 + nb * 16 + (lane & 15);      // 0..1023
            int k = kk * 32 + (lane >> 4) * 8 + e;
            int row = (fcol < 512) ? k : (256 + k);
            WabP[t] = f2bf(Wsc0[row * 512 + (fcol & 511)]);
            continue;
        }
        t -= NWAB;
        if (t < NCAT) {
            int e = t & 127, k = (t >> 7) & 255, r = (t >> 15) & 3, d = (t >> 17) & 1, l = t >> 18;
            const float* src = (d == 0) ? Wfw : Wbw;
            float v = src[((l * 4 + r) * 256 + k) * 128 + e];
            WcatT[(l * 1024 + d * 512 + r * 128 + e) * 256 + k] = f2bf(v);
            continue;
        }
        t -= NCAT;
        if (t < NLIN) {
            int d = t & 255, f = (t >> 8) & 255, l = t >> 16;
            WlinT[(l * 256 + d) * 256 + f] = f2bf(Wlin[(l * 256 + f) * 256 + d]);
            continue;
        }
        t -= NLIN;
        if (t < NW1P) {
            int e = t & 7, lane = (t >> 3) & 63, kap = t >> 9;
            int fp = kap * 32 + (lane >> 4) * 8 + e;         // f'
            int w = fp >> 6, q = (fp >> 2) & 15, nb = fp & 3;
            int f = w * 64 + nb * 16 + q;                    // inverse permutation
            int r = lane & 15;
            W1p[t] = (r < 4) ? f2bf(Wsc1[f * 4 + r]) : (unsigned short)0;
            continue;
        }
        t -= NW1P;
        {
            int f = t & 255, l = t >> 8;
            float s = 0.f;
            if (f < 128) { for (int r = 0; r < 4; ++r) s += bbw[(l * 4 + r) * 128 + f]; }
            else         { for (int r = 0; r < 4; ++r) s += bfw[(l * 4 + r) * 128 + (f - 128)]; }
            bsumS[l * 256 + f] = s;
        }
    }
}

// ---------------- uv: U=E@W0a (+b0, nb-paired pack), V=E@W0b (fp32 row-major) via MFMA ----------------
__global__ __launch_bounds__(512) void uv_kernel(const unsigned short* __restrict__ E16,
                                                 const unsigned short* __restrict__ WabP,
                                                 const float* __restrict__ bsc0,
                                                 unsigned short* __restrict__ Upk,
                                                 float* __restrict__ V) {
    __shared__ unsigned short sE[32 * 256];   // 16 KB swizzled
    const int jt = blockIdx.x;
    const int tid = threadIdx.x, lane = tid & 63, w = tid >> 6;
    const int l15 = lane & 15, l4 = lane >> 4;
#pragma unroll
    for (int it = 0; it < 2; ++it) {
        int u = it * 512 + tid;
        int row = u >> 5, slot = u & 31;
        uint4 v = *(const uint4*)(E16 + (jt * 32 + row) * 256 + slot * 8);
        *(uint4*)((char*)sE + row * 512 + ((slot * 16) ^ ((row & 7) << 4))) = v;
    }
    __syncthreads();
    const bf16x8* Wab8 = (const bf16x8*)WabP;
    f32x4 acc[2][8];
#pragma unroll
    for (int a_ = 0; a_ < 2; ++a_)
#pragma unroll
        for (int b_ = 0; b_ < 8; ++b_) acc[a_][b_] = (f32x4){0.f, 0.f, 0.f, 0.f};
#pragma unroll
    for (int kk = 0; kk < 8; ++kk) {
        bf16x8 af[2];
#pragma unroll
        for (int mbl = 0; mbl < 2; ++mbl) {
            int row = mbl * 16 + l15;
            af[mbl] = *(const bf16x8*)((char*)sE + row * 512 + ((kk * 64 + l4 * 16) ^ ((row & 7) << 4)));
        }
#pragma unroll
        for (int nb = 0; nb < 8; ++nb) {
            int wf = 2 * w + (nb >> 2);
            bf16x8 bfr = Wab8[((wf * 4 + (nb & 3)) * 8 + kk) * 64 + lane];
#pragma unroll
            for (int mbl = 0; mbl < 2; ++mbl)
                acc[mbl][nb] = __builtin_amdgcn_mfma_f32_16x16x32_bf16(af[mbl], bfr, acc[mbl][nb], 0, 0, 0);
        }
    }
#pragma unroll
    for (int mbl = 0; mbl < 2; ++mbl) {
        int j_base = jt * 32 + mbl * 16 + l4 * 4;
#pragma unroll
        for (int nb8 = 0; nb8 < 8; ++nb8) {
            int f_g = (2 * w + (nb8 >> 2)) * 64 + (nb8 & 3) * 16 + l15;
            if (f_g < 512) {
                float b0f = bsc0[f_g];
                ushort4 o;
                o.x = f2bf(acc[mbl][nb8][0] + b0f);
                o.y = f2bf(acc[mbl][nb8][1] + b0f);
                o.z = f2bf(acc[mbl][nb8][2] + b0f);
                o.w = f2bf(acc[mbl][nb8][3] + b0f);
                int jtp = j_base >> 6, mbp = (j_base >> 4) & 3;
                int wp = f_g >> 6, nbp = (f_g >> 4) & 3;
                int lanep = l4 * 16 + l15;
                *(ushort4*)(Upk + ((((jtp * 8 + wp) * 4 + mbp) * 2 + (nbp >> 1)) * 64 + lanep) * 8 + (nbp & 1) * 4) = o;
            } else {
                int fv = f_g - 512;
#pragma unroll
                for (int reg = 0; reg < 4; ++reg)
                    V[(j_base + reg) * 512 + fv] = acc[mbl][nb8][reg];
            }
        }
    }
}

// ---------------- pair scorer: 2 i-rows per block, shared W0p/Upk/Ej streams ----------------
__global__ __launch_bounds__(512, 2) void pair_kernel(
    const unsigned short* __restrict__ E16, const unsigned short* __restrict__ W0p,
    const unsigned short* __restrict__ Upk, const float* __restrict__ V,
    const unsigned short* __restrict__ W1p, const float* __restrict__ b1,
    unsigned short* __restrict__ A16) {

    __shared__ unsigned short bufL[2 * 64 * 256];  // 64 KB: prod0|prod1, reused as H (64x512)
    __shared__ float vrow[2][512];                 // 4 KB
    __shared__ float scoresL[2][256];              // 2 KB

    const int i0 = blockIdx.x * 2, i1 = i0 + 1;
    const int jt = blockIdx.y;
    const int j0 = jt * 64;
    const int tid = threadIdx.x;
    const int lane = tid & 63;
    const int w = tid >> 6;
    const int l15 = lane & 15, l4 = lane >> 4;

    vrow[0][tid] = V[i0 * 512 + tid];
    vrow[1][tid] = V[i1 * 512 + tid];
    if (tid < 256) { scoresL[0][tid] = b1[tid & 3]; scoresL[1][tid] = b1[tid & 3]; }

    // ---- stage both product tiles (64 j x 256 k each) from E16 ----
    {
        int m = tid >> 3;
        int slot = tid & 7;
        const bf16x8* ejp  = (const bf16x8*)(E16 + (j0 + m) * 256 + slot * 32);
        const bf16x8* ei0p = (const bf16x8*)(E16 + i0 * 256 + slot * 32);
        const bf16x8* ei1p = (const bf16x8*)(E16 + i1 * 256 + slot * 32);
        char* base = (char*)bufL;
#pragma unroll
        for (int c = 0; c < 4; ++c) {
            bf16x8 ej = ejp[c], e0 = ei0p[c], e1 = ei1p[c];
            uint4 v0, v1;
            unsigned* p0 = (unsigned*)&v0;
            unsigned* p1 = (unsigned*)&v1;
#pragma unroll
            for (int e2 = 0; e2 < 4; ++e2) {
                float jl = bf2f((unsigned short)ej[e2 * 2]), jh = bf2f((unsigned short)ej[e2 * 2 + 1]);
                p0[e2] = pack2bf(jl * bf2f((unsigned short)e0[e2 * 2]), jh * bf2f((unsigned short)e0[e2 * 2 + 1]));
                p1[e2] = pack2bf(jl * bf2f((unsigned short)e1[e2 * 2]), jh * bf2f((unsigned short)e1[e2 * 2 + 1]));
            }
            int off = m * 512 + ((slot * 64 + c * 16) ^ ((m & 7) << 4));
            *(uint4*)(base + off) = v0;
            *(uint4*)(base + 32768 + off) = v1;
        }
    }

    // ---- acc init = U(+b0) + V[i] ----
    f32x4 acc0[4][4], acc1[4][4];
#pragma unroll
    for (int mb = 0; mb < 4; ++mb)
#pragma unroll
        for (int nbh = 0; nbh < 2; ++nbh) {
            uint4 u4 = *(const uint4*)(Upk + ((((jt * 8 + w) * 4 + mb) * 2 + nbh) * 64 + lane) * 8);
            const unsigned short* us = (const unsigned short*)&u4;
#pragma unroll
            for (int h = 0; h < 2; ++h) {
                int nb = nbh * 2 + h;
                float v0f = vrow[0][w * 64 + nb * 16 + l15];
                float v1f = vrow[1][w * 64 + nb * 16 + l15];
#pragma unroll
                for (int reg = 0; reg < 4; ++reg) {
                    float uu = bf2f(us[h * 4 + reg]);
                    acc0[mb][nb][reg] = uu + v0f;
                    acc1[mb][nb][reg] = uu + v1f;
                }
            }
        }
    __syncthreads();

    // ---- main loop: 32 MFMA per kk (16 per i) ----
    const char* pbase = (const char*)bufL;
    const bf16x8* Wp8 = (const bf16x8*)W0p;
#pragma unroll
    for (int kk = 0; kk < 8; ++kk) {
        bf16x8 bfr[4];
#pragma unroll
        for (int nb = 0; nb < 4; ++nb)
            bfr[nb] = Wp8[((w * 4 + nb) * 8 + kk) * 64 + lane];
        bf16x8 afr[4];
#pragma unroll
        for (int mb = 0; mb < 4; ++mb) {
            int row = mb * 16 + l15;
            afr[mb] = *(const bf16x8*)(pbase + row * 512 + ((kk * 64 + l4 * 16) ^ ((row & 7) << 4)));
        }
#pragma unroll
        for (int mb = 0; mb < 4; ++mb)
#pragma unroll
            for (int nb = 0; nb < 4; ++nb)
                acc0[mb][nb] = __builtin_amdgcn_mfma_f32_16x16x32_bf16(afr[mb], bfr[nb], acc0[mb][nb], 0, 0, 0);
#pragma unroll
        for (int mb = 0; mb < 4; ++mb) {
            int row = mb * 16 + l15;
            afr[mb] = *(const bf16x8*)(pbase + 32768 + row * 512 + ((kk * 64 + l4 * 16) ^ ((row & 7) << 4)));
        }
#pragma unroll
        for (int mb = 0; mb < 4; ++mb)
#pragma unroll
            for (int nb = 0; nb < 4; ++nb)
                acc1[mb][nb] = __builtin_amdgcn_mfma_f32_16x16x32_bf16(afr[mb], bfr[nb], acc1[mb][nb], 0, 0, 0);
    }
    __syncthreads();   // prod tiles dead; H overlay next

    // ---- epilogue per i: H = relu(acc) (f' = w*64+l15*4+nb), S = H @ W1p' ----
    char* hb = (char*)bufL;
    const bf16x8* W1p8 = (const bf16x8*)W1p;
    bf16x8 w1f[2];
#pragma unroll
    for (int kl = 0; kl < 2; ++kl) w1f[kl] = W1p8[(w * 2 + kl) * 64 + lane];

#pragma unroll
    for (int ii = 0; ii < 2; ++ii) {
#pragma unroll
        for (int mb = 0; mb < 4; ++mb)
#pragma unroll
            for (int reg = 0; reg < 4; ++reg) {
                int rl = mb * 16 + l4 * 4 + reg;
                f32x4* A = (ii == 0) ? &acc0[mb][0] : &acc1[mb][0];
                float h0 = fmaxf(A[0][reg], 0.f);
                float h1 = fmaxf(A[1][reg], 0.f);
                float h2 = fmaxf(A[2][reg], 0.f);
                float h3 = fmaxf(A[3][reg], 0.f);
                uint2 val;
                val.x = pack2bf(h0, h1);
                val.y = pack2bf(h2, h3);
                *(uint2*)(hb + rl * 1024 + ((w * 128 + l15 * 8) ^ ((rl & 7) << 4))) = val;
            }
        __syncthreads();
        f32x4 accS[4];
#pragma unroll
        for (int mb = 0; mb < 4; ++mb) {
            accS[mb] = (f32x4){0.f, 0.f, 0.f, 0.f};
            int rl = mb * 16 + l15;
#pragma unroll
            for (int kl = 0; kl < 2; ++kl) {
                bf16x8 ha = *(const bf16x8*)(hb + rl * 1024 + (((w * 2 + kl) * 64 + l4 * 16) ^ ((rl & 7) << 4)));
                accS[mb] = __builtin_amdgcn_mfma_f32_16x16x32_bf16(ha, w1f[kl], accS[mb], 0, 0, 0);
            }
        }
        if (l15 < 4) {
#pragma unroll
            for (int mb = 0; mb < 4; ++mb)
#pragma unroll
                for (int reg = 0; reg < 4; ++reg)
                    atomicAdd(&scoresL[ii][(mb * 16 + l4 * 4 + reg) * 4 + l15], accS[mb][reg]);
        }
        __syncthreads();
    }

    // ---- softmax + A write (both i in parallel lane groups) ----
    if (tid < 128) {
        int ii = tid >> 6, m = tid & 63;
        int j = j0 + m, ic = i0 + ii;
        float s0 = scoresL[ii][m * 4 + 0], s1 = scoresL[ii][m * 4 + 1];
        float sA = scoresL[ii][m * 4 + 2], sB = scoresL[ii][m * 4 + 3];
        float mx = fmaxf(fmaxf(s0, s1), fmaxf(sA, sB));
        float e0 = __expf(s0 - mx), e1 = __expf(s1 - mx), e2 = __expf(sA - mx), e3 = __expf(sB - mx);
        float inv = 1.f / (e0 + e1 + e2 + e3);
        float p_[4] = {e0 * inv, e1 * inv, e2 * inv, e3 * inv};
        if (j == ic) { p_[0] = p_[1] = p_[2] = p_[3] = 0.f; }
#pragma unroll
        for (int r = 0; r < 4; ++r)
            A16[(r * 512 + ic) * 512 + j] = f2bf(p_[r]);
    }
}

// ---------------- LDS panel helpers ----------------
template<int K>
__device__ __forceinline__ void stageP(unsigned short* lds, const unsigned short* g, int ldg, int tid) {
    constexpr int SLOTS = K / 8;
#pragma unroll
    for (int it = 0; it < (32 * SLOTS) / 256; ++it) {
        int u = it * 256 + tid;
        int row = u / SLOTS, slot = u % SLOTS;
        uint4 v = *(const uint4*)(g + row * ldg + slot * 8);
        *(uint4*)((char*)lds + row * (K * 2) + ((slot * 16) ^ ((row & 7) << 4))) = v;
    }
}
__device__ __forceinline__ void stage64(unsigned short* lds, const unsigned short* g, int ldg, int tid) {
#pragma unroll
    for (int it = 0; it < 8; ++it) {
        int u = it * 256 + tid;
        int row = u >> 5, slot = u & 31;
        uint4 v = *(const uint4*)(g + row * ldg + slot * 8);
        *(uint4*)((char*)lds + row * 512 + ((slot * 16) ^ ((row & 7) << 4))) = v;
    }
}
template<int K>
__device__ __forceinline__ bf16x8 fragP(const unsigned short* lds, int row, int kc, int l4) {
    return *(const bf16x8*)((const char*)lds + row * (K * 2) + ((((kc * 4 + l4) * 16) ^ ((row & 7) << 4))));
}

// ---------------- c1: supT = WcatT . x16^T  (+ fused A->AT transpose jobs, l=0) ----------------
__global__ __launch_bounds__(256) void c1_kernel(const unsigned short* __restrict__ WcatT,
                                                 const unsigned short* __restrict__ x16,
                                                 unsigned short* __restrict__ supT,
                                                 const unsigned short* __restrict__ A16,
                                                 unsigned short* __restrict__ AT16, int l) {
    __shared__ unsigned short lA[32 * 256], lB[32 * 256];
    int tid = threadIdx.x;
    if (blockIdx.y >= 16) {
        auto t = (unsigned short(*)[65])lA;
        int job = (blockIdx.y - 16) * 32 + blockIdx.x;
        int r = job >> 6, ty = (job >> 3) & 7, tx = job & 7;
        const unsigned short* src = A16 + (r * 512 + ty * 64) * 512 + tx * 64;
        unsigned short* dst = AT16 + (r * 512 + tx * 64) * 512 + ty * 64;
#pragma unroll
        for (int it = 0; it < 2; ++it) {
            int u = it * 256 + tid, row = u >> 3, c8 = (u & 7) * 8;
            uint4 v = *(const uint4*)(src + row * 512 + c8);
            const unsigned short* p = (const unsigned short*)&v;
#pragma unroll
            for (int e = 0; e < 8; ++e) t[c8 + e][row] = p[e];
        }
        __syncthreads();
#pragma unroll
        for (int it = 0; it < 2; ++it) {
            int u = it * 256 + tid, row = u >> 3, c8 = (u & 7) * 8;
            uint4 v; unsigned short* p = (unsigned short*)&v;
#pragma unroll
            for (int e = 0; e < 8; ++e) p[e] = t[row][c8 + e];
            *(uint4*)(dst + row * 512 + c8) = v;
        }
        return;
    }
    int c0 = blockIdx.x * 32, jt0 = blockIdx.y * 32;
    int lane = tid & 63, w = tid >> 6;
    int wr = (w >> 1) * 16, wc = (w & 1) * 16;
    int l15 = lane & 15, l4 = lane >> 4;
    stageP<256>(lA, WcatT + l * 262144 + c0 * 256, 256, tid);
    stageP<256>(lB, x16 + jt0 * 256, 256, tid);
    __syncthreads();
    f32x4 a0 = {0.f,0.f,0.f,0.f}, a1 = {0.f,0.f,0.f,0.f};
#pragma unroll
    for (int kc = 0; kc < 8; kc += 2) {
        a0 = __builtin_amdgcn_mfma_f32_16x16x32_bf16(fragP<256>(lA, wr + l15, kc, l4),
                                                     fragP<256>(lB, wc + l15, kc, l4), a0, 0, 0, 0);
        a1 = __builtin_amdgcn_mfma_f32_16x16x32_bf16(fragP<256>(lA, wr + l15, kc + 1, l4),
                                                     fragP<256>(lB, wc + l15, kc + 1, l4), a1, 0, 0, 0);
    }
    f32x4 acc = a0 + a1;
#pragma unroll
    for (int reg = 0; reg < 4; ++reg) {
        int c = c0 + wr + l4 * 4 + reg;
        int j = jt0 + wc + l15;
        supT[c * 512 + j] = f2bf(acc[reg]);
    }
}

// ---------------- c2 (split-k): Pc2[s] = partial (A|AT)[r] @ sup[r], 64x64 tiles ----------------
__global__ __launch_bounds__(256) void c2_kernel(const unsigned short* __restrict__ A16,
                                                 const unsigned short* __restrict__ AT16,
                                                 const unsigned short* __restrict__ supT,
                                                 float* __restrict__ Pc2) {
    __shared__ unsigned short lA[64 * 256], lB[64 * 256];
    int i0 = blockIdx.x * 64, f0 = blockIdx.y * 64;
    int s = blockIdx.z, r = s >> 1, kh = s & 1;
    bool bw = (f0 < 128);
    int e0 = bw ? f0 : (f0 - 128);
    const unsigned short* Am = bw ? AT16 : A16;
    int tid = threadIdx.x, lane = tid & 63, w = tid >> 6;
    int wr = (w >> 1) * 32, wc = (w & 1) * 32;
    int l15 = lane & 15, l4 = lane >> 4;
    stage64(lA, Am + (r * 512 + i0) * 512 + kh * 256, 512, tid);
    stage64(lB, supT + ((bw ? 512 : 0) + r * 128 + e0) * 512 + kh * 256, 512, tid);
    __syncthreads();
    f32x4 acc[2][2];
#pragma unroll
    for (int a_ = 0; a_ < 2; ++a_)
#pragma unroll
        for (int b_ = 0; b_ < 2; ++b_) acc[a_][b_] = (f32x4){0.f, 0.f, 0.f, 0.f};
#pragma unroll
    for (int kc = 0; kc < 8; ++kc) {
        bf16x8 af[2], bf_[2];
#pragma unroll
        for (int mb = 0; mb < 2; ++mb) af[mb] = fragP<256>(lA, wr + mb * 16 + l15, kc, l4);
#pragma unroll
        for (int nb = 0; nb < 2; ++nb) bf_[nb] = fragP<256>(lB, wc + nb * 16 + l15, kc, l4);
#pragma unroll
        for (int mb = 0; mb < 2; ++mb)
#pragma unroll
            for (int nb = 0; nb < 2; ++nb)
                acc[mb][nb] = __builtin_amdgcn_mfma_f32_16x16x32_bf16(af[mb], bf_[nb], acc[mb][nb], 0, 0, 0);
    }
    float* dst = Pc2 + s * 131072;
#pragma unroll
    for (int mb = 0; mb < 2; ++mb)
#pragma unroll
        for (int nb = 0; nb < 2; ++nb)
#pragma unroll
            for (int reg = 0; reg < 4; ++reg)
                dst[(i0 + wr + mb * 16 + l4 * 4 + reg) * 256 + f0 + wc + nb * 16 + l15] = acc[mb][nb][reg];
}

// ---------------- c3: xnew = relu(sum_s Pc2 + bsum) @ Wlin + blin + xold ----------------
__global__ __launch_bounds__(256) void c3_kernel(const float* __restrict__ Pc2,
                                                 const float* __restrict__ bsumS,
                                                 const unsigned short* __restrict__ WlinT,
                                                 const float* __restrict__ blin,
                                                 const float* __restrict__ xold,
                                                 float* __restrict__ xnew,
                                                 unsigned short* __restrict__ x16out, int l) {
    __shared__ unsigned short lA[32 * 256], lB[32 * 256];
    int i0 = blockIdx.x * 32, d0 = blockIdx.y * 32;
    int tid = threadIdx.x, lane = tid & 63, w = tid >> 6;
    int wr = (w >> 1) * 16, wc = (w & 1) * 16;
    int l15 = lane & 15, l4 = lane >> 4;
#pragma unroll
    for (int g = 0; g < 4; ++g) {
        int u = g * 256 + tid;
        int row = u >> 5, k8 = (u & 31) * 8;
        float s[8] = {0,0,0,0,0,0,0,0};
#pragma unroll
        for (int s8 = 0; s8 < 8; ++s8) {
            const float4* p = (const float4*)(Pc2 + s8 * 131072 + (i0 + row) * 256 + k8);
            float4 a = p[0], b = p[1];
            s[0] += a.x; s[1] += a.y; s[2] += a.z; s[3] += a.w;
            s[4] += b.x; s[5] += b.y; s[6] += b.z; s[7] += b.w;
        }
        uint4 v;
        unsigned* vp = (unsigned*)&v;
#pragma unroll
        for (int e2 = 0; e2 < 4; ++e2) {
            float lo = fmaxf(s[e2 * 2] + bsumS[l * 256 + k8 + e2 * 2], 0.f);
            float hi = fmaxf(s[e2 * 2 + 1] + bsumS[l * 256 + k8 + e2 * 2 + 1], 0.f);
            vp[e2] = pack2bf(lo, hi);
        }
        *(uint4*)((char*)lA + row * 512 + ((k8 * 2) ^ ((row & 7) << 4))) = v;
    }
    stageP<256>(lB, WlinT + l * 65536 + d0 * 256, 256, tid);
    __syncthreads();
    f32x4 a0 = {0.f,0.f,0.f,0.f}, a1 = {0.f,0.f,0.f,0.f};
#pragma unroll
    for (int kc = 0; kc < 8; kc += 2) {
        a0 = __builtin_amdgcn_mfma_f32_16x16x32_bf16(fragP<256>(lA, wr + l15, kc, l4),
                                                     fragP<256>(lB, wc + l15, kc, l4), a0, 0, 0, 0);
        a1 = __builtin_amdgcn_mfma_f32_16x16x32_bf16(fragP<256>(lA, wr + l15, kc + 1, l4),
                                                     fragP<256>(lB, wc + l15, kc + 1, l4), a1, 0, 0, 0);
    }
    f32x4 acc = a0 + a1;
#pragma unroll
    for (int reg = 0; reg < 4; ++reg) {
        int ii = i0 + wr + l4 * 4 + reg;
        int dd = d0 + wc + l15;
        float vv = acc[reg] + blin[l * 256 + dd] + xold[ii * 256 + dd];
        xnew[ii * 256 + dd] = vv;
        x16out[ii * 256 + dd] = f2bf(vv);
    }
}

extern "C" void kernel_launch(void* const* d_in, const int* in_sizes, int n_in,
                              void* d_out, int out_size, void* d_ws, size_t ws_size,
                              hipStream_t stream) {
    const float* E    = (const float*)d_in[0];
    const float* Wsc0 = (const float*)d_in[1];
    const float* bsc0 = (const float*)d_in[2];
    const float* Wsc1 = (const float*)d_in[3];
    const float* bsc1 = (const float*)d_in[4];
    const float* Wfw  = (const float*)d_in[5];
    const float* bfw  = (const float*)d_in[6];
    const float* Wbw  = (const float*)d_in[7];
    const float* bbw  = (const float*)d_in[8];
    const float* Wlin = (const float*)d_in[9];
    const float* blin = (const float*)d_in[10];
    float* out = (float*)d_out;

    char* ws = (char*)d_ws;
    size_t off = 0;
    unsigned short* E16   = (unsigned short*)(ws + off); off += 512 * 256 * 2;        // 256 KB
    unsigned short* W0p   = (unsigned short*)(ws + off); off += 512 * 256 * 2;        // 256 KB
    unsigned short* WabP  = (unsigned short*)(ws + off); off += 1024 * 256 * 2;       // 512 KB
    unsigned short* WcatT = (unsigned short*)(ws + off); off += 2 * 1024 * 256 * 2;   // 1 MB
    unsigned short* WlinT = (unsigned short*)(ws + off); off += 2 * 256 * 256 * 2;    // 256 KB
    float* bsumS          = (float*)(ws + off);          off += 2 * 256 * 4;          // 2 KB
    unsigned short* Upk   = (unsigned short*)(ws + off); off += 512 * 512 * 2;        // 512 KB
    float* V              = (float*)(ws + off);          off += 512 * 512 * 4;        // 1 MB
    unsigned short* W1p   = (unsigned short*)(ws + off); off += 16 * 64 * 8 * 2;      // 16 KB
    unsigned short* A16   = (unsigned short*)(ws + off); off += 4 * 512 * 512 * 2;    // 2 MB
    unsigned short* AT16  = (unsigned short*)(ws + off); off += 4 * 512 * 512 * 2;    // 2 MB
    unsigned short* supT  = (unsigned short*)(ws + off); off += 1024 * 512 * 2;       // 1 MB
    float* Pc2            = (float*)(ws + off);          off += 8 * 512 * 256 * 4;    // 4 MB
    float* xf1            = (float*)(ws + off);          off += 512 * 256 * 4;        // 512 KB
    unsigned short* x16_1 = (unsigned short*)(ws + off); off += 512 * 256 * 2;        // 256 KB

    prep_kernel<<<512, 512, 0, stream>>>(E, Wsc0, Wsc1, Wfw, bfw, Wbw, bbw, Wlin,
                                         E16, W0p, WabP, WcatT, WlinT, bsumS, W1p);
    uv_kernel<<<16, 512, 0, stream>>>(E16, WabP, bsc0, Upk, V);
    pair_kernel<<<dim3(256, 8), 512, 0, stream>>>(E16, W0p, Upk, V, W1p, bsc1, A16);

    for (int l = 0; l < 2; ++l) {
        const unsigned short* xin16 = (l == 0) ? E16 : x16_1;
        const float* xoldf = (l == 0) ? E : xf1;
        float* xout = (l == 0) ? xf1 : out;
        c1_kernel<<<dim3(32, (l == 0) ? 24 : 16), 256, 0, stream>>>(WcatT, xin16, supT, A16, AT16, l);
        c2_kernel<<<dim3(8, 4, 8), 256, 0, stream>>>(A16, AT16, supT, Pc2);
        c3_kernel<<<dim3(16, 8), 256, 0, stream>>>(Pc2, bsumS, WlinT, blin, xoldf, xout, x16_1, l);
    }
    (void)in_sizes; (void)n_in; (void)out_size; (void)ws_size;
}